// Round 1
// baseline (2001.003 us; speedup 1.0000x reference)
//
#include <hip/hip_runtime.h>
#include <math.h>

#define BATCH   2
#define N_NODES 10000
#define E_EDGES 160000
#define ND      128
#define ED      64
#define HID     256
#define MSG_IN  320   // 2*ND + ED
#define UPD_IN  384   // ND + HID
#define TE      16    // edges per block
#define TN      16    // nodes per block

__device__ __forceinline__ float gelu_tanh(float x) {
    // jax.nn.gelu default (approximate=True)
    float x3 = x * x * x;
    float t = tanhf(0.7978845608028654f * (x + 0.044715f * x3));
    return 0.5f * x * (1.0f + t);
}

__global__ __launch_bounds__(256) void edge_mlp_scatter(
    const float* __restrict__ nodef,   // [B,N,128]
    const int*   __restrict__ eidx,    // [B,E,2]
    const float* __restrict__ edgef,   // [B,E,64]
    const float* __restrict__ W1m,     // [320,256]
    const float* __restrict__ b1m,     // [256]
    const float* __restrict__ W2m,     // [256,256]
    const float* __restrict__ b2m,     // [256]
    float* __restrict__ agg)           // [B,N,256] (pre-zeroed)
{
    __shared__ float s_msg[TE][MSG_IN];
    __shared__ float s_h[TE][HID];
    __shared__ int   s_src[TE];
    __shared__ int   s_dst[TE];

    const int tid = threadIdx.x;
    const int be0 = blockIdx.x * TE;   // global edge id base in [0, B*E)

    if (tid < TE) {
        int be = be0 + tid;
        int b  = be / E_EDGES;
        int e  = be - b * E_EDGES;
        int2 se = ((const int2*)eidx)[b * E_EDGES + e];
        s_src[tid] = b * N_NODES + se.x;
        s_dst[tid] = b * N_NODES + se.y;
    }
    __syncthreads();

    // Gather msg_in = [src(128) | dst(128) | edge(64)] -> 80 float4 per edge
    for (int vi = tid; vi < TE * 80; vi += 256) {
        int el = vi / 80;
        int p  = vi - el * 80;
        if (p < 32) {
            ((float4*)&s_msg[el][0])[p] =
                ((const float4*)nodef)[(long long)s_src[el] * 32 + p];
        } else if (p < 64) {
            ((float4*)&s_msg[el][128])[p - 32] =
                ((const float4*)nodef)[(long long)s_dst[el] * 32 + (p - 32)];
        } else {
            ((float4*)&s_msg[el][256])[p - 64] =
                ((const float4*)edgef)[(long long)(be0 + el) * 16 + (p - 64)];
        }
    }
    __syncthreads();

    // Layer 1: h = gelu(msg_in @ W1m + b1m); thread j owns hidden unit j
    const int j = tid;
    float acc[TE];
    #pragma unroll
    for (int e = 0; e < TE; ++e) acc[e] = 0.f;
    for (int i = 0; i < MSG_IN; ++i) {
        float w = W1m[i * HID + j];
        #pragma unroll
        for (int e = 0; e < TE; ++e) acc[e] += s_msg[e][i] * w;
    }
    {
        float bj = b1m[j];
        #pragma unroll
        for (int e = 0; e < TE; ++e) s_h[e][j] = gelu_tanh(acc[e] + bj);
    }
    __syncthreads();

    // Layer 2: messages = h @ W2m + b2m; scatter-add into agg[dst]
    #pragma unroll
    for (int e = 0; e < TE; ++e) acc[e] = 0.f;
    for (int k = 0; k < HID; ++k) {
        float w = W2m[k * HID + j];
        #pragma unroll
        for (int e = 0; e < TE; ++e) acc[e] += s_h[e][k] * w;
    }
    {
        float b2 = b2m[j];
        #pragma unroll
        for (int e = 0; e < TE; ++e) {
            atomicAdd(&agg[(long long)s_dst[e] * HID + j], acc[e] + b2);
        }
    }
}

__global__ __launch_bounds__(256) void node_mlp(
    const float* __restrict__ nodef,   // [B,N,128]
    const float* __restrict__ agg,     // [B,N,256]
    const float* __restrict__ W1u,     // [384,256]
    const float* __restrict__ b1u,     // [256]
    const float* __restrict__ W2u,     // [256,128]
    const float* __restrict__ b2u,     // [128]
    float* __restrict__ out)           // [B,N,128]
{
    __shared__ float s_in[TN][UPD_IN];
    __shared__ float s_u[TN][HID];

    const int tid = threadIdx.x;
    const int n0  = blockIdx.x * TN;   // global node id base in [0, B*N)

    // Gather upd_in = [node(128) | agg(256)] -> 96 float4 per node
    for (int vi = tid; vi < TN * 96; vi += 256) {
        int nl = vi / 96;
        int p  = vi - nl * 96;
        long long n = n0 + nl;
        if (p < 32) {
            ((float4*)&s_in[nl][0])[p] = ((const float4*)nodef)[n * 32 + p];
        } else {
            ((float4*)&s_in[nl][128])[p - 32] = ((const float4*)agg)[n * 64 + (p - 32)];
        }
    }
    __syncthreads();

    // Layer 1: u = gelu(upd_in @ W1u + b1u)
    const int j = tid;
    float acc[TN];
    #pragma unroll
    for (int e = 0; e < TN; ++e) acc[e] = 0.f;
    for (int i = 0; i < UPD_IN; ++i) {
        float w = W1u[i * HID + j];
        #pragma unroll
        for (int e = 0; e < TN; ++e) acc[e] += s_in[e][i] * w;
    }
    {
        float bj = b1u[j];
        #pragma unroll
        for (int e = 0; e < TN; ++e) s_u[e][j] = gelu_tanh(acc[e] + bj);
    }
    __syncthreads();

    // Layer 2: out = u @ W2u + b2u; 256 threads = 128 outputs x 2 node halves
    const int o  = tid & 127;
    const int e0 = (tid >> 7) * 8;
    float acc2[8];
    #pragma unroll
    for (int e = 0; e < 8; ++e) acc2[e] = 0.f;
    for (int k = 0; k < HID; ++k) {
        float w = W2u[k * ND + o];
        #pragma unroll
        for (int e = 0; e < 8; ++e) acc2[e] += s_u[e0 + e][k] * w;
    }
    {
        float b2 = b2u[o];
        #pragma unroll
        for (int e = 0; e < 8; ++e) {
            out[(long long)(n0 + e0 + e) * ND + o] = acc2[e] + b2;
        }
    }
}

extern "C" void kernel_launch(void* const* d_in, const int* in_sizes, int n_in,
                              void* d_out, int out_size, void* d_ws, size_t ws_size,
                              hipStream_t stream) {
    const float* nodef = (const float*)d_in[0];
    const int*   eidx  = (const int*)  d_in[1];
    const float* edgef = (const float*)d_in[2];
    const float* W1m   = (const float*)d_in[3];
    const float* b1m   = (const float*)d_in[4];
    const float* W2m   = (const float*)d_in[5];
    const float* b2m   = (const float*)d_in[6];
    const float* W1u   = (const float*)d_in[7];
    const float* b1u   = (const float*)d_in[8];
    const float* W2u   = (const float*)d_in[9];
    const float* b2u   = (const float*)d_in[10];

    float* out = (float*)d_out;
    float* agg = (float*)d_ws;    // [B, N, HID] fp32 accumulate buffer

    size_t agg_bytes = (size_t)BATCH * N_NODES * HID * sizeof(float);
    hipMemsetAsync(agg, 0, agg_bytes, stream);

    edge_mlp_scatter<<<(BATCH * E_EDGES) / TE, 256, 0, stream>>>(
        nodef, eidx, edgef, W1m, b1m, W2m, b2m, agg);

    node_mlp<<<(BATCH * N_NODES) / TN, 256, 0, stream>>>(
        nodef, agg, W1u, b1u, W2u, b2u, out);
}

// Round 4
// 615.165 us; speedup vs baseline: 3.2528x; 3.2528x over previous
//
#include <hip/hip_runtime.h>
#include <hip/hip_bf16.h>
#include <math.h>

#define BATCH   2
#define N_NODES 10000
#define E_EDGES 160000
#define ND      128
#define ED      64
#define HID     256
#define K1      320   // 2*ND + ED
#define K2      256
#define UPD_IN  384   // ND + HID
#define TM      64    // edges per block (edge kernel)
#define LDA     40    // A-tile LDS row stride (bf16), 32 + 8 pad
#define LDB     40    // B-tile LDS row stride (bf16)
#define LDH     264   // H LDS row stride (bf16), 256 + 8 pad
#define TN      16    // nodes per block (node kernel)

typedef __attribute__((ext_vector_type(8))) short bf16x8;   // MFMA A/B fragment (8 bf16)
typedef __attribute__((ext_vector_type(4))) float f32x4;    // MFMA C/D fragment

__device__ __forceinline__ float gelu_tanh(float x) {
    float x3 = x * x * x;
    float t = tanhf(0.7978845608028654f * (x + 0.044715f * x3));
    return 0.5f * x * (1.0f + t);
}

__device__ __forceinline__ unsigned short f2bf(float f) {
    __hip_bfloat16 h = __float2bfloat16(f);
    return *reinterpret_cast<unsigned short*>(&h);
}

// ---------- prep kernels ----------

__global__ __launch_bounds__(256) void f32_to_bf16_vec(
    const float* __restrict__ in, unsigned short* __restrict__ out, int n4)
{
    int i = blockIdx.x * blockDim.x + threadIdx.x;
    if (i < n4) {
        float4 v = ((const float4*)in)[i];
        ushort4 o;
        o.x = f2bf(v.x); o.y = f2bf(v.y); o.z = f2bf(v.z); o.w = f2bf(v.w);
        ((ushort4*)out)[i] = o;
    }
}

// wt[n*K + k] = bf16(w[k*N + n])   (weights stored n-major for MFMA B frags)
__global__ __launch_bounds__(256) void w_transpose_bf16(
    const float* __restrict__ w, unsigned short* __restrict__ wt, int K, int N)
{
    int id = blockIdx.x * blockDim.x + threadIdx.x;
    if (id < K * N) {
        int k = id % K;
        int n = id / K;
        wt[id] = f2bf(w[k * N + n]);
    }
}

// ---------- edge MLP (MFMA) + scatter ----------

__global__ __launch_bounds__(256) void edge_mlp_mfma(
    const unsigned short* __restrict__ nodef_bf,  // [B*N,128] bf16
    const int*            __restrict__ eidx,      // [B,E,2]
    const float*          __restrict__ edgef,     // [B*E,64] fp32 (converted inline)
    const unsigned short* __restrict__ w1t,       // [256][320] bf16 (n-major)
    const float*          __restrict__ b1m,       // [256]
    const unsigned short* __restrict__ w2t,       // [256][256] bf16 (n-major)
    const float*          __restrict__ b2m,       // [256]
    float* __restrict__ agg)                      // [B*N,256] f32, pre-zeroed
{
    __shared__ __align__(16) unsigned short sA[TM * LDA];   //  5120 B
    __shared__ __align__(16) unsigned short sB[HID * LDB];  // 20480 B
    __shared__ __align__(16) unsigned short sH[TM * LDH];   // 33792 B
    __shared__ int s_src[TM];
    __shared__ int s_dst[TM];

    const int tid  = threadIdx.x;
    const int wave = tid >> 6;
    const int lane = tid & 63;
    const int quad = lane >> 4;
    const int r16  = lane & 15;
    const int be0  = blockIdx.x * TM;   // global edge base in [0, B*E)

    if (tid < TM) {
        int be = be0 + tid;
        int b  = be / E_EDGES;
        int e  = be - b * E_EDGES;
        int2 se = ((const int2*)eidx)[b * E_EDGES + e];
        s_src[tid] = b * N_NODES + se.x;
        s_dst[tid] = b * N_NODES + se.y;
    }
    __syncthreads();

    f32x4 acc[4][4];   // [m-tile][n-tile]
    #pragma unroll
    for (int mt = 0; mt < 4; ++mt)
        #pragma unroll
        for (int nt = 0; nt < 4; ++nt)
            acc[mt][nt] = (f32x4){0.f, 0.f, 0.f, 0.f};

    // ---- Layer 1: C1[64x256] = msg_in[64x320] @ W1 ----
    for (int ks = 0; ks < K1 / 32; ++ks) {
        const int k0 = ks * 32;
        // stage A: gathered rows; thread t -> edge t/4, 16B chunk t%4
        {
            int e  = tid >> 2, c = tid & 3;
            int kk = k0 + c * 8;                  // bf16 col in msg_in
            if (kk < 128) {
                *(float4*)&sA[e * LDA + c * 8] =
                    *(const float4*)(nodef_bf + (size_t)s_src[e] * ND + kk);
            } else if (kk < 256) {
                *(float4*)&sA[e * LDA + c * 8] =
                    *(const float4*)(nodef_bf + (size_t)s_dst[e] * ND + (kk - 128));
            } else {
                // edge features: fp32 source, convert inline (8 floats -> 8 bf16)
                const float* fp = edgef + (size_t)(be0 + e) * ED + (kk - 256);
                float4 v0 = *(const float4*)fp;
                float4 v1 = *(const float4*)(fp + 4);
                ushort4 o0, o1;
                o0.x = f2bf(v0.x); o0.y = f2bf(v0.y); o0.z = f2bf(v0.z); o0.w = f2bf(v0.w);
                o1.x = f2bf(v1.x); o1.y = f2bf(v1.y); o1.z = f2bf(v1.z); o1.w = f2bf(v1.w);
                *(ushort4*)&sA[e * LDA + c * 8]     = o0;
                *(ushort4*)&sA[e * LDA + c * 8 + 4] = o1;
            }
        }
        // stage B: 256x32 tile of w1t; 1024 16B chunks
        #pragma unroll
        for (int ci = 0; ci < 4; ++ci) {
            int c = tid + ci * 256;
            int n = c >> 2, sub = c & 3;
            *(float4*)&sB[n * LDB + sub * 8] =
                *(const float4*)&w1t[(size_t)n * K1 + k0 + sub * 8];
        }
        __syncthreads();

        bf16x8 af[4], bfg[4];
        #pragma unroll
        for (int mt = 0; mt < 4; ++mt)
            af[mt] = *(const bf16x8*)&sA[(mt * 16 + r16) * LDA + quad * 8];
        #pragma unroll
        for (int nt = 0; nt < 4; ++nt)
            bfg[nt] = *(const bf16x8*)&sB[(wave * 64 + nt * 16 + r16) * LDB + quad * 8];
        #pragma unroll
        for (int mt = 0; mt < 4; ++mt)
            #pragma unroll
            for (int nt = 0; nt < 4; ++nt)
                acc[mt][nt] = __builtin_amdgcn_mfma_f32_16x16x32_bf16(
                    af[mt], bfg[nt], acc[mt][nt], 0, 0, 0);
        __syncthreads();
    }

    // layer-1 epilogue: gelu(acc + bias) -> sH (bf16), C layout: col=r16, row=quad*4+r
    #pragma unroll
    for (int nt = 0; nt < 4; ++nt) {
        int n = wave * 64 + nt * 16 + r16;
        float bias = b1m[n];
        #pragma unroll
        for (int mt = 0; mt < 4; ++mt) {
            #pragma unroll
            for (int r = 0; r < 4; ++r) {
                int m = mt * 16 + quad * 4 + r;
                sH[m * LDH + n] = f2bf(gelu_tanh(acc[mt][nt][r] + bias));
            }
        }
        #pragma unroll
        for (int mt = 0; mt < 4; ++mt)
            acc[mt][nt] = (f32x4){0.f, 0.f, 0.f, 0.f};
    }

    // ---- Layer 2: C2[64x256] = H[64x256] @ W2 ----
    for (int ks = 0; ks < K2 / 32; ++ks) {
        const int k0 = ks * 32;
        #pragma unroll
        for (int ci = 0; ci < 4; ++ci) {
            int c = tid + ci * 256;
            int n = c >> 2, sub = c & 3;
            *(float4*)&sB[n * LDB + sub * 8] =
                *(const float4*)&w2t[(size_t)n * K2 + k0 + sub * 8];
        }
        __syncthreads();   // also makes sH writes visible on first iter

        bf16x8 af[4], bfg[4];
        #pragma unroll
        for (int mt = 0; mt < 4; ++mt)
            af[mt] = *(const bf16x8*)&sH[(mt * 16 + r16) * LDH + k0 + quad * 8];
        #pragma unroll
        for (int nt = 0; nt < 4; ++nt)
            bfg[nt] = *(const bf16x8*)&sB[(wave * 64 + nt * 16 + r16) * LDB + quad * 8];
        #pragma unroll
        for (int mt = 0; mt < 4; ++mt)
            #pragma unroll
            for (int nt = 0; nt < 4; ++nt)
                acc[mt][nt] = __builtin_amdgcn_mfma_f32_16x16x32_bf16(
                    af[mt], bfg[nt], acc[mt][nt], 0, 0, 0);
        __syncthreads();
    }

    // layer-2 epilogue: scatter-add messages into agg[dst]
    #pragma unroll
    for (int nt = 0; nt < 4; ++nt) {
        int n = wave * 64 + nt * 16 + r16;
        float bias = b2m[n];
        #pragma unroll
        for (int mt = 0; mt < 4; ++mt) {
            #pragma unroll
            for (int r = 0; r < 4; ++r) {
                int m = mt * 16 + quad * 4 + r;
                atomicAdd(&agg[(size_t)s_dst[m] * HID + n], acc[mt][nt][r] + bias);
            }
        }
    }
}

// ---------- node MLP (fp32) ----------

__global__ __launch_bounds__(256) void node_mlp(
    const float* __restrict__ nodef,   // [B,N,128]
    const float* __restrict__ agg,     // [B,N,256]
    const float* __restrict__ W1u,     // [384,256]
    const float* __restrict__ b1u,     // [256]
    const float* __restrict__ W2u,     // [256,128]
    const float* __restrict__ b2u,     // [128]
    float* __restrict__ out)           // [B,N,128]
{
    __shared__ float s_in[TN][UPD_IN];
    __shared__ float s_u[TN][HID];

    const int tid = threadIdx.x;
    const int n0  = blockIdx.x * TN;

    for (int vi = tid; vi < TN * 96; vi += 256) {
        int nl = vi / 96;
        int p  = vi - nl * 96;
        long long n = n0 + nl;
        if (p < 32) {
            ((float4*)&s_in[nl][0])[p] = ((const float4*)nodef)[n * 32 + p];
        } else {
            ((float4*)&s_in[nl][128])[p - 32] = ((const float4*)agg)[n * 64 + (p - 32)];
        }
    }
    __syncthreads();

    const int j = tid;
    float acc[TN];
    #pragma unroll
    for (int e = 0; e < TN; ++e) acc[e] = 0.f;
    for (int i = 0; i < UPD_IN; ++i) {
        float w = W1u[i * HID + j];
        #pragma unroll
        for (int e = 0; e < TN; ++e) acc[e] += s_in[e][i] * w;
    }
    {
        float bj = b1u[j];
        #pragma unroll
        for (int e = 0; e < TN; ++e) s_u[e][j] = gelu_tanh(acc[e] + bj);
    }
    __syncthreads();

    const int o  = tid & 127;
    const int e0 = (tid >> 7) * 8;
    float acc2[8];
    #pragma unroll
    for (int e = 0; e < 8; ++e) acc2[e] = 0.f;
    for (int k = 0; k < HID; ++k) {
        float w = W2u[k * ND + o];
        #pragma unroll
        for (int e = 0; e < 8; ++e) acc2[e] += s_u[e0 + e][k] * w;
    }
    {
        float b2 = b2u[o];
        #pragma unroll
        for (int e = 0; e < 8; ++e) {
            out[(long long)(n0 + e0 + e) * ND + o] = acc2[e] + b2;
        }
    }
}

// ---------- launch ----------
// ws usage: agg only = 20,480,000 B (exactly what Round 1 proved safe).
// bf16 scratch (nodef_bf 5.12 MB + w1t 160 KB + w2t 128 KB = 5.42 MB) lives
// inside d_out (10.24 MB): prep kernels write it, edge_mlp_mfma reads it,
// node_mlp overwrites d_out with the final output strictly afterwards
// (same-stream ordering). Harness only validates d_out after the launch.

extern "C" void kernel_launch(void* const* d_in, const int* in_sizes, int n_in,
                              void* d_out, int out_size, void* d_ws, size_t ws_size,
                              hipStream_t stream) {
    const float* nodef = (const float*)d_in[0];
    const int*   eidx  = (const int*)  d_in[1];
    const float* edgef = (const float*)d_in[2];
    const float* W1m   = (const float*)d_in[3];
    const float* b1m   = (const float*)d_in[4];
    const float* W2m   = (const float*)d_in[5];
    const float* b2m   = (const float*)d_in[6];
    const float* W1u   = (const float*)d_in[7];
    const float* b1u   = (const float*)d_in[8];
    const float* W2u   = (const float*)d_in[9];
    const float* b2u   = (const float*)d_in[10];
    float* out = (float*)d_out;

    // workspace: fp32 aggregate only
    float* agg = (float*)d_ws;   // [B*N, 256] = 20,480,000 B

    // scratch stashed in d_out (overwritten by node_mlp at the end)
    char* ob = (char*)d_out;
    unsigned short* nodef_bf = (unsigned short*)ob;                       // 5,120,000 B
    unsigned short* w1t = (unsigned short*)(ob + 5120000);                //   163,840 B
    unsigned short* w2t = (unsigned short*)(ob + 5120000 + 163840);      //   131,072 B
    // total 5,414,912 B < out bytes (10,240,000 B)

    hipMemsetAsync(agg, 0, (size_t)BATCH * N_NODES * HID * sizeof(float), stream);

    {
        int n4 = BATCH * N_NODES * ND / 4;       // 640,000
        f32_to_bf16_vec<<<(n4 + 255) / 256, 256, 0, stream>>>(nodef, nodef_bf, n4);
    }
    w_transpose_bf16<<<(K1 * HID + 255) / 256, 256, 0, stream>>>(W1m, w1t, K1, HID);
    w_transpose_bf16<<<(K2 * HID + 255) / 256, 256, 0, stream>>>(W2m, w2t, K2, HID);

    edge_mlp_mfma<<<(BATCH * E_EDGES) / TM, 256, 0, stream>>>(
        nodef_bf, eidx, edgef, w1t, b1m, w2t, b2m, agg);

    node_mlp<<<(BATCH * N_NODES) / TN, 256, 0, stream>>>(
        nodef, agg, W1u, b1u, W2u, b2u, out);
}

// Round 5
// 537.145 us; speedup vs baseline: 3.7253x; 1.1453x over previous
//
#include <hip/hip_runtime.h>
#include <hip/hip_bf16.h>
#include <math.h>

#define BATCH   2
#define N_NODES 10000
#define E_EDGES 160000
#define BN      (BATCH * N_NODES)       // 20000
#define BE      (BATCH * E_EDGES)       // 320000
#define ND      128
#define ED      64
#define HID     256
#define K1      320   // 2*ND + ED
#define K2      256
#define K1U     384   // ND + HID
#define NOUT    128
#define TM      64    // rows per block
#define LDA     40    // A-tile LDS row stride (bf16)
#define LDB     40    // B-tile LDS row stride (bf16)
#define LDH     264   // H LDS row stride (bf16)
#define LDF     260   // fbuf row stride (fp32)

typedef __attribute__((ext_vector_type(8))) short bf16x8;
typedef __attribute__((ext_vector_type(4))) float f32x4;

__device__ __forceinline__ float gelu_tanh(float x) {
    float x3 = x * x * x;
    float t = tanhf(0.7978845608028654f * (x + 0.044715f * x3));
    return 0.5f * x * (1.0f + t);
}

__device__ __forceinline__ unsigned short f2bf(float f) {
    __hip_bfloat16 h = __float2bfloat16(f);
    return *reinterpret_cast<unsigned short*>(&h);
}

// ---------- prep kernels ----------

__global__ __launch_bounds__(256) void f32_to_bf16_vec(
    const float* __restrict__ in, unsigned short* __restrict__ out, int n4)
{
    int i = blockIdx.x * blockDim.x + threadIdx.x;
    if (i < n4) {
        float4 v = ((const float4*)in)[i];
        ushort4 o;
        o.x = f2bf(v.x); o.y = f2bf(v.y); o.z = f2bf(v.z); o.w = f2bf(v.w);
        ((ushort4*)out)[i] = o;
    }
}

__global__ __launch_bounds__(256) void w_transpose_bf16(
    const float* __restrict__ w, unsigned short* __restrict__ wt, int K, int N)
{
    int id = blockIdx.x * blockDim.x + threadIdx.x;
    if (id < K * N) {
        int k = id % K;
        int n = id / K;
        wt[id] = f2bf(w[k * N + n]);
    }
}

// histogram of flat dst
__global__ __launch_bounds__(256) void dst_hist(
    const int* __restrict__ eidx, int* __restrict__ hist)
{
    int e = blockIdx.x * blockDim.x + threadIdx.x;
    if (e < BE) {
        int dst = eidx[2 * e + 1];
        int b   = e / E_EDGES;
        atomicAdd(&hist[b * N_NODES + dst], 1);
    }
}

// exclusive prefix sum over BN bins (single block, 1024 threads)
__global__ __launch_bounds__(1024) void scan_bins(
    const int* __restrict__ hist, int* __restrict__ offs)
{
    __shared__ int buf[1024];
    __shared__ int s_carry;
    int tid = threadIdx.x;
    if (tid == 0) s_carry = 0;
    __syncthreads();
    for (int base = 0; base < BN; base += 1024) {
        int i = base + tid;
        int v = (i < BN) ? hist[i] : 0;
        buf[tid] = v;
        __syncthreads();
        #pragma unroll
        for (int d = 1; d < 1024; d <<= 1) {
            int t = (tid >= d) ? buf[tid - d] : 0;
            __syncthreads();
            buf[tid] += t;
            __syncthreads();
        }
        int incl = buf[tid];
        int excl = incl - v + s_carry;
        if (i < BN) offs[i] = excl;
        __syncthreads();
        if (tid == 1023) s_carry += incl;
        __syncthreads();
    }
}

// scatter edge ids into dst-sorted order
__global__ __launch_bounds__(256) void dst_scatter(
    const int* __restrict__ eidx, int* __restrict__ offs, int* __restrict__ perm)
{
    int e = blockIdx.x * blockDim.x + threadIdx.x;
    if (e < BE) {
        int dst  = eidx[2 * e + 1];
        int b    = e / E_EDGES;
        int pos  = atomicAdd(&offs[b * N_NODES + dst], 1);
        perm[pos] = e;
    }
}

// ---------- edge MLP (MFMA) + sorted scatter ----------

#define EDGE_SMEM (5120 + 66560)   // sA + max(sB+sH, fbuf)

__global__ __launch_bounds__(256) void edge_mlp_mfma(
    const unsigned short* __restrict__ nodef_bf,  // [BN,128] bf16
    const int*            __restrict__ eidx,      // [BE,2]
    const float*          __restrict__ edgef,     // [BE,64] fp32
    const int*            __restrict__ perm,      // [BE] dst-sorted edge ids
    const unsigned short* __restrict__ w1t,       // [256][320] bf16 n-major
    const float*          __restrict__ b1m,
    const unsigned short* __restrict__ w2t,       // [256][256] bf16 n-major
    const float*          __restrict__ b2m,
    float* __restrict__ agg)                      // [BN,256] f32, pre-zeroed
{
    __shared__ __align__(16) char smem[EDGE_SMEM];
    unsigned short* sA = (unsigned short*)smem;                    //  5120 B
    unsigned short* sB = (unsigned short*)(smem + 5120);           // 20480 B
    unsigned short* sH = (unsigned short*)(smem + 5120 + 20480);   // 33792 B
    float* fbuf = (float*)(smem + 5120);                           // 64*260*4 B (aliases sB+sH)
    __shared__ int s_src[TM];
    __shared__ int s_dst[TM];
    __shared__ int s_eid[TM];

    const int tid  = threadIdx.x;
    const int wave = tid >> 6;
    const int lane = tid & 63;
    const int quad = lane >> 4;
    const int r16  = lane & 15;
    const int be0  = blockIdx.x * TM;

    if (tid < TM) {
        int eid = perm[be0 + tid];
        int b   = eid / E_EDGES;
        int2 se = ((const int2*)eidx)[eid];
        s_eid[tid] = eid;
        s_src[tid] = b * N_NODES + se.x;
        s_dst[tid] = b * N_NODES + se.y;
    }
    __syncthreads();

    f32x4 acc[4][4];
    #pragma unroll
    for (int mt = 0; mt < 4; ++mt)
        #pragma unroll
        for (int nt = 0; nt < 4; ++nt)
            acc[mt][nt] = (f32x4){0.f, 0.f, 0.f, 0.f};

    // ---- Layer 1 ----
    for (int ks = 0; ks < K1 / 32; ++ks) {
        const int k0 = ks * 32;
        {
            int e  = tid >> 2, c = tid & 3;
            int kk = k0 + c * 8;
            if (kk < 128) {
                *(float4*)&sA[e * LDA + c * 8] =
                    *(const float4*)(nodef_bf + (size_t)s_src[e] * ND + kk);
            } else if (kk < 256) {
                *(float4*)&sA[e * LDA + c * 8] =
                    *(const float4*)(nodef_bf + (size_t)s_dst[e] * ND + (kk - 128));
            } else {
                const float* fp = edgef + (size_t)s_eid[e] * ED + (kk - 256);
                float4 v0 = *(const float4*)fp;
                float4 v1 = *(const float4*)(fp + 4);
                ushort4 o0, o1;
                o0.x = f2bf(v0.x); o0.y = f2bf(v0.y); o0.z = f2bf(v0.z); o0.w = f2bf(v0.w);
                o1.x = f2bf(v1.x); o1.y = f2bf(v1.y); o1.z = f2bf(v1.z); o1.w = f2bf(v1.w);
                *(ushort4*)&sA[e * LDA + c * 8]     = o0;
                *(ushort4*)&sA[e * LDA + c * 8 + 4] = o1;
            }
        }
        #pragma unroll
        for (int ci = 0; ci < 4; ++ci) {
            int c = tid + ci * 256;
            int n = c >> 2, sub = c & 3;
            *(float4*)&sB[n * LDB + sub * 8] =
                *(const float4*)&w1t[(size_t)n * K1 + k0 + sub * 8];
        }
        __syncthreads();

        bf16x8 af[4], bfg[4];
        #pragma unroll
        for (int mt = 0; mt < 4; ++mt)
            af[mt] = *(const bf16x8*)&sA[(mt * 16 + r16) * LDA + quad * 8];
        #pragma unroll
        for (int nt = 0; nt < 4; ++nt)
            bfg[nt] = *(const bf16x8*)&sB[(wave * 64 + nt * 16 + r16) * LDB + quad * 8];
        #pragma unroll
        for (int mt = 0; mt < 4; ++mt)
            #pragma unroll
            for (int nt = 0; nt < 4; ++nt)
                acc[mt][nt] = __builtin_amdgcn_mfma_f32_16x16x32_bf16(
                    af[mt], bfg[nt], acc[mt][nt], 0, 0, 0);
        __syncthreads();
    }

    // layer-1 epilogue -> sH
    #pragma unroll
    for (int nt = 0; nt < 4; ++nt) {
        int n = wave * 64 + nt * 16 + r16;
        float bias = b1m[n];
        #pragma unroll
        for (int mt = 0; mt < 4; ++mt) {
            #pragma unroll
            for (int r = 0; r < 4; ++r) {
                int m = mt * 16 + quad * 4 + r;
                sH[m * LDH + n] = f2bf(gelu_tanh(acc[mt][nt][r] + bias));
            }
        }
        #pragma unroll
        for (int mt = 0; mt < 4; ++mt)
            acc[mt][nt] = (f32x4){0.f, 0.f, 0.f, 0.f};
    }

    // ---- Layer 2 ----
    for (int ks = 0; ks < K2 / 32; ++ks) {
        const int k0 = ks * 32;
        #pragma unroll
        for (int ci = 0; ci < 4; ++ci) {
            int c = tid + ci * 256;
            int n = c >> 2, sub = c & 3;
            *(float4*)&sB[n * LDB + sub * 8] =
                *(const float4*)&w2t[(size_t)n * K2 + k0 + sub * 8];
        }
        __syncthreads();

        bf16x8 af[4], bfg[4];
        #pragma unroll
        for (int mt = 0; mt < 4; ++mt)
            af[mt] = *(const bf16x8*)&sH[(mt * 16 + r16) * LDH + k0 + quad * 8];
        #pragma unroll
        for (int nt = 0; nt < 4; ++nt)
            bfg[nt] = *(const bf16x8*)&sB[(wave * 64 + nt * 16 + r16) * LDB + quad * 8];
        #pragma unroll
        for (int mt = 0; mt < 4; ++mt)
            #pragma unroll
            for (int nt = 0; nt < 4; ++nt)
                acc[mt][nt] = __builtin_amdgcn_mfma_f32_16x16x32_bf16(
                    af[mt], bfg[nt], acc[mt][nt], 0, 0, 0);
        __syncthreads();
    }

    // ---- epilogue: dump C (+bias) to fbuf, run-reduce by sorted dst ----
    #pragma unroll
    for (int nt = 0; nt < 4; ++nt) {
        int n = wave * 64 + nt * 16 + r16;
        float bias = b2m[n];
        #pragma unroll
        for (int mt = 0; mt < 4; ++mt) {
            #pragma unroll
            for (int r = 0; r < 4; ++r) {
                int m = mt * 16 + quad * 4 + r;
                fbuf[m * LDF + n] = acc[mt][nt][r] + bias;
            }
        }
    }
    __syncthreads();

    {
        const int cc = tid;   // column 0..255
        int   cur  = s_dst[0];
        float racc = fbuf[cc];
        for (int m = 1; m < TM; ++m) {
            int   d = s_dst[m];          // wave-uniform
            float v = fbuf[m * LDF + cc];
            if (d != cur) {
                atomicAdd(&agg[(size_t)cur * HID + cc], racc);
                cur = d; racc = v;
            } else {
                racc += v;
            }
        }
        atomicAdd(&agg[(size_t)cur * HID + cc], racc);
    }
}

// ---------- node MLP (MFMA, fused two layers) ----------

__global__ __launch_bounds__(256) void node_mlp_mfma(
    const float* __restrict__ nodef,   // [BN,128] fp32
    const float* __restrict__ agg,     // [BN,256] fp32
    const float* __restrict__ W1u,     // [384,256] fp32 k-major
    const float* __restrict__ b1u,
    const float* __restrict__ W2u,     // [256,128] fp32 k-major
    const float* __restrict__ b2u,
    float* __restrict__ out)           // [BN,128] fp32
{
    __shared__ __align__(16) unsigned short sA[TM * LDA];
    __shared__ __align__(16) unsigned short sB[HID * LDB];
    __shared__ __align__(16) unsigned short sH[TM * LDH];

    const int tid  = threadIdx.x;
    const int wave = tid >> 6;
    const int lane = tid & 63;
    const int quad = lane >> 4;
    const int r16  = lane & 15;
    const int n0   = blockIdx.x * TM;

    f32x4 acc[4][4];
    #pragma unroll
    for (int mt = 0; mt < 4; ++mt)
        #pragma unroll
        for (int nt = 0; nt < 4; ++nt)
            acc[mt][nt] = (f32x4){0.f, 0.f, 0.f, 0.f};

    // ---- Layer 1: u = gelu([nodef|agg] @ W1u + b1u), K=384 ----
    for (int ks = 0; ks < K1U / 32; ++ks) {
        const int k0 = ks * 32;
        // A: 64 rows x 32 cols, fp32 -> bf16 inline
        {
            int e  = tid >> 2, c = tid & 3;
            int row = n0 + e; if (row >= BN) row = BN - 1;
            int kk = k0 + c * 8;
            const float* fp = (kk < 128)
                ? nodef + (size_t)row * ND + kk
                : agg   + (size_t)row * HID + (kk - 128);
            float4 v0 = *(const float4*)fp;
            float4 v1 = *(const float4*)(fp + 4);
            ushort4 o0, o1;
            o0.x = f2bf(v0.x); o0.y = f2bf(v0.y); o0.z = f2bf(v0.z); o0.w = f2bf(v0.w);
            o1.x = f2bf(v1.x); o1.y = f2bf(v1.y); o1.z = f2bf(v1.z); o1.w = f2bf(v1.w);
            *(ushort4*)&sA[e * LDA + c * 8]     = o0;
            *(ushort4*)&sA[e * LDA + c * 8 + 4] = o1;
        }
        // B: 256 n x 32 k, transpose+convert from W1u fp32
        #pragma unroll
        for (int it = 0; it < 4; ++it) {
            int u  = it * 256 + tid;
            int kp = u & 15;          // k-pair
            int nq = u >> 4;          // n-quad
            int k  = k0 + 2 * kp;
            float4 v0 = *(const float4*)&W1u[(size_t)k * HID + 4 * nq];
            float4 v1 = *(const float4*)&W1u[(size_t)(k + 1) * HID + 4 * nq];
            const float* a0 = (const float*)&v0;
            const float* a1 = (const float*)&v1;
            #pragma unroll
            for (int j = 0; j < 4; ++j) {
                unsigned int pk = (unsigned int)f2bf(a0[j]) |
                                  ((unsigned int)f2bf(a1[j]) << 16);
                *(unsigned int*)&sB[(4 * nq + j) * LDB + 2 * kp] = pk;
            }
        }
        __syncthreads();

        bf16x8 af[4], bfg[4];
        #pragma unroll
        for (int mt = 0; mt < 4; ++mt)
            af[mt] = *(const bf16x8*)&sA[(mt * 16 + r16) * LDA + quad * 8];
        #pragma unroll
        for (int nt = 0; nt < 4; ++nt)
            bfg[nt] = *(const bf16x8*)&sB[(wave * 64 + nt * 16 + r16) * LDB + quad * 8];
        #pragma unroll
        for (int mt = 0; mt < 4; ++mt)
            #pragma unroll
            for (int nt = 0; nt < 4; ++nt)
                acc[mt][nt] = __builtin_amdgcn_mfma_f32_16x16x32_bf16(
                    af[mt], bfg[nt], acc[mt][nt], 0, 0, 0);
        __syncthreads();
    }

    // layer-1 epilogue -> sH
    #pragma unroll
    for (int nt = 0; nt < 4; ++nt) {
        int n = wave * 64 + nt * 16 + r16;
        float bias = b1u[n];
        #pragma unroll
        for (int mt = 0; mt < 4; ++mt) {
            #pragma unroll
            for (int r = 0; r < 4; ++r) {
                int m = mt * 16 + quad * 4 + r;
                sH[m * LDH + n] = f2bf(gelu_tanh(acc[mt][nt][r] + bias));
            }
        }
    }

    // ---- Layer 2: out = u @ W2u + b2u, 128 cols; wave w owns cols w*32..w*32+31 ----
    f32x4 acc2[4][2];
    #pragma unroll
    for (int mt = 0; mt < 4; ++mt)
        #pragma unroll
        for (int nt = 0; nt < 2; ++nt)
            acc2[mt][nt] = (f32x4){0.f, 0.f, 0.f, 0.f};

    for (int ks = 0; ks < K2 / 32; ++ks) {
        const int k0 = ks * 32;
        // B: 128 n x 32 k from W2u fp32
        #pragma unroll
        for (int it = 0; it < 2; ++it) {
            int u  = it * 256 + tid;
            int kp = u & 15;
            int nq = u >> 4;          // 0..31
            int k  = k0 + 2 * kp;
            float4 v0 = *(const float4*)&W2u[(size_t)k * NOUT + 4 * nq];
            float4 v1 = *(const float4*)&W2u[(size_t)(k + 1) * NOUT + 4 * nq];
            const float* a0 = (const float*)&v0;
            const float* a1 = (const float*)&v1;
            #pragma unroll
            for (int j = 0; j < 4; ++j) {
                unsigned int pk = (unsigned int)f2bf(a0[j]) |
                                  ((unsigned int)f2bf(a1[j]) << 16);
                *(unsigned int*)&sB[(4 * nq + j) * LDB + 2 * kp] = pk;
            }
        }
        __syncthreads();   // sH writes (first iter) + sB staging visible

        bf16x8 af[4], bfg[2];
        #pragma unroll
        for (int mt = 0; mt < 4; ++mt)
            af[mt] = *(const bf16x8*)&sH[(mt * 16 + r16) * LDH + k0 + quad * 8];
        #pragma unroll
        for (int nt = 0; nt < 2; ++nt)
            bfg[nt] = *(const bf16x8*)&sB[(wave * 32 + nt * 16 + r16) * LDB + quad * 8];
        #pragma unroll
        for (int mt = 0; mt < 4; ++mt)
            #pragma unroll
            for (int nt = 0; nt < 2; ++nt)
                acc2[mt][nt] = __builtin_amdgcn_mfma_f32_16x16x32_bf16(
                    af[mt], bfg[nt], acc2[mt][nt], 0, 0, 0);
        __syncthreads();
    }

    // store
    #pragma unroll
    for (int nt = 0; nt < 2; ++nt) {
        int n = wave * 32 + nt * 16 + r16;
        float bias = b2u[n];
        #pragma unroll
        for (int mt = 0; mt < 4; ++mt) {
            #pragma unroll
            for (int r = 0; r < 4; ++r) {
                int m = mt * 16 + quad * 4 + r;
                if (n0 + m < BN)
                    out[(size_t)(n0 + m) * NOUT + n] = acc2[mt][nt][r] + bias;
            }
        }
    }
}

// ---------- launch ----------
// ws usage: agg only = 20,480,000 B (proven safe in Round 4).
// d_out stash (read only by prep + edge kernel; node kernel overwrites all of
// d_out strictly afterwards in stream order):
//   nodef_bf [0 .. 5,120,000)
//   w1t      [5,120,000 .. 5,283,840)
//   w2t      [5,283,840 .. 5,414,912)
//   hist     [5,414,912 .. 5,494,912)
//   offs     [5,494,912 .. 5,574,912)
//   perm     [5,574,912 .. 6,854,912)     total < 10,240,000 B

extern "C" void kernel_launch(void* const* d_in, const int* in_sizes, int n_in,
                              void* d_out, int out_size, void* d_ws, size_t ws_size,
                              hipStream_t stream) {
    const float* nodef = (const float*)d_in[0];
    const int*   eidx  = (const int*)  d_in[1];
    const float* edgef = (const float*)d_in[2];
    const float* W1m   = (const float*)d_in[3];
    const float* b1m   = (const float*)d_in[4];
    const float* W2m   = (const float*)d_in[5];
    const float* b2m   = (const float*)d_in[6];
    const float* W1u   = (const float*)d_in[7];
    const float* b1u   = (const float*)d_in[8];
    const float* W2u   = (const float*)d_in[9];
    const float* b2u   = (const float*)d_in[10];
    float* out = (float*)d_out;

    float* agg = (float*)d_ws;   // [BN, 256] fp32 = 20,480,000 B

    char* ob = (char*)d_out;
    unsigned short* nodef_bf = (unsigned short*)ob;
    unsigned short* w1t  = (unsigned short*)(ob + 5120000);
    unsigned short* w2t  = (unsigned short*)(ob + 5283840);
    int* hist            = (int*)(ob + 5414912);
    int* offs            = (int*)(ob + 5494912);
    int* perm            = (int*)(ob + 5574912);

    hipMemsetAsync(agg, 0, (size_t)BN * HID * sizeof(float), stream);
    hipMemsetAsync(hist, 0, BN * sizeof(int), stream);

    {
        int n4 = BN * ND / 4;
        f32_to_bf16_vec<<<(n4 + 255) / 256, 256, 0, stream>>>(nodef, nodef_bf, n4);
    }
    w_transpose_bf16<<<(K1 * HID + 255) / 256, 256, 0, stream>>>(W1m, w1t, K1, HID);
    w_transpose_bf16<<<(K2 * HID + 255) / 256, 256, 0, stream>>>(W2m, w2t, K2, HID);

    dst_hist<<<(BE + 255) / 256, 256, 0, stream>>>(eidx, hist);
    scan_bins<<<1, 1024, 0, stream>>>(hist, offs);
    dst_scatter<<<(BE + 255) / 256, 256, 0, stream>>>(eidx, offs, perm);

    edge_mlp_mfma<<<BE / TM, 256, 0, stream>>>(
        nodef_bf, eidx, edgef, perm, w1t, b1m, w2t, b2m, agg);

    node_mlp_mfma<<<(BN + TM - 1) / TM, 256, 0, stream>>>(
        nodef, agg, W1u, b1u, W2u, b2u, out);
}

// Round 7
// 472.604 us; speedup vs baseline: 4.2340x; 1.1366x over previous
//
#include <hip/hip_runtime.h>
#include <hip/hip_bf16.h>
#include <math.h>

#define BATCH   2
#define N_NODES 10000
#define E_EDGES 160000
#define BN      (BATCH * N_NODES)       // 20000
#define BE      (BATCH * E_EDGES)       // 320000
#define ND      128
#define ED      64
#define HID     256
#define K1      320   // 2*ND + ED
#define K2      256
#define K1U     384   // ND + HID
#define NOUT    128
#define TM      64    // rows per block
#define LDA     40    // A-tile LDS row stride (bf16)
#define LDB     40    // B-tile LDS row stride (bf16)
#define LDH     264   // H LDS row stride (bf16)
#define LDF     260   // fbuf row stride (fp32)

typedef __attribute__((ext_vector_type(8))) short bf16x8;
typedef __attribute__((ext_vector_type(4))) float f32x4;

// fast tanh-gelu: tanh(u) = 1 - 2/(exp(2u)+1); both tails saturate correctly.
__device__ __forceinline__ float gelu_tanh(float x) {
    float u = 0.7978845608028654f * (x + 0.044715f * x * x * x);
    float e = __expf(2.0f * u);
    float t = 1.0f - 2.0f * __builtin_amdgcn_rcpf(e + 1.0f);
    return 0.5f * x * (1.0f + t);
}

__device__ __forceinline__ unsigned short f2bf(float f) {
    __hip_bfloat16 h = __float2bfloat16(f);
    return *reinterpret_cast<unsigned short*>(&h);
}

// ---------- prep kernels ----------

__global__ __launch_bounds__(256) void f32_to_bf16_vec(
    const float* __restrict__ in, unsigned short* __restrict__ out, int n4)
{
    int i = blockIdx.x * blockDim.x + threadIdx.x;
    if (i < n4) {
        float4 v = ((const float4*)in)[i];
        ushort4 o;
        o.x = f2bf(v.x); o.y = f2bf(v.y); o.z = f2bf(v.z); o.w = f2bf(v.w);
        ((ushort4*)out)[i] = o;
    }
}

__global__ __launch_bounds__(256) void w_transpose_bf16(
    const float* __restrict__ w, unsigned short* __restrict__ wt, int K, int N)
{
    int id = blockIdx.x * blockDim.x + threadIdx.x;
    if (id < K * N) {
        int k = id % K;
        int n = id / K;
        wt[id] = f2bf(w[k * N + n]);
    }
}

__global__ __launch_bounds__(256) void dst_hist(
    const int* __restrict__ eidx, int* __restrict__ hist)
{
    int e = blockIdx.x * blockDim.x + threadIdx.x;
    if (e < BE) {
        int dst = eidx[2 * e + 1];
        int b   = e / E_EDGES;
        atomicAdd(&hist[b * N_NODES + dst], 1);
    }
}

__global__ __launch_bounds__(1024) void scan_bins(
    const int* __restrict__ hist, int* __restrict__ offs)
{
    __shared__ int buf[1024];
    __shared__ int s_carry;
    int tid = threadIdx.x;
    if (tid == 0) s_carry = 0;
    __syncthreads();
    for (int base = 0; base < BN; base += 1024) {
        int i = base + tid;
        int v = (i < BN) ? hist[i] : 0;
        buf[tid] = v;
        __syncthreads();
        #pragma unroll
        for (int d = 1; d < 1024; d <<= 1) {
            int t = (tid >= d) ? buf[tid - d] : 0;
            __syncthreads();
            buf[tid] += t;
            __syncthreads();
        }
        int incl = buf[tid];
        int excl = incl - v + s_carry;
        if (i < BN) offs[i] = excl;
        __syncthreads();
        if (tid == 1023) s_carry += incl;
        __syncthreads();
    }
}

__global__ __launch_bounds__(256) void dst_scatter(
    const int* __restrict__ eidx, int* __restrict__ offs, int* __restrict__ perm)
{
    int e = blockIdx.x * blockDim.x + threadIdx.x;
    if (e < BE) {
        int dst  = eidx[2 * e + 1];
        int b    = e / E_EDGES;
        int pos  = atomicAdd(&offs[b * N_NODES + dst], 1);
        perm[pos] = e;
    }
}

// ---------- edge MLP (MFMA) + sorted scatter ----------

#define EDGE_SMEM (5120 + 66560)   // sA + max(sB+sH, fbuf)

__global__ __launch_bounds__(256) void edge_mlp_mfma(
    const unsigned short* __restrict__ nodef_bf,
    const int*            __restrict__ eidx,
    const float*          __restrict__ edgef,
    const int*            __restrict__ perm,
    const unsigned short* __restrict__ w1t,       // [256][320] bf16 n-major
    const float*          __restrict__ b1m,
    const unsigned short* __restrict__ w2t,       // [256][256] bf16 n-major
    const float*          __restrict__ b2m,
    float* __restrict__ agg)
{
    __shared__ __align__(16) char smem[EDGE_SMEM];
    unsigned short* sA = (unsigned short*)smem;                    //  5120 B
    unsigned short* sB = (unsigned short*)(smem + 5120);           // 20480 B
    unsigned short* sH = (unsigned short*)(smem + 5120 + 20480);   // 33792 B
    float* fbuf = (float*)(smem + 5120);                           // aliases sB+sH
    __shared__ int s_src[TM];
    __shared__ int s_dst[TM];
    __shared__ int s_eid[TM];

    const int tid  = threadIdx.x;
    const int wave = tid >> 6;
    const int lane = tid & 63;
    const int quad = lane >> 4;
    const int r16  = lane & 15;
    const int be0  = blockIdx.x * TM;

    if (tid < TM) {
        int eid = perm[be0 + tid];
        int b   = eid / E_EDGES;
        int2 se = ((const int2*)eidx)[eid];
        s_eid[tid] = eid;
        s_src[tid] = b * N_NODES + se.x;
        s_dst[tid] = b * N_NODES + se.y;
    }
    __syncthreads();

    f32x4 acc[4][4];
    #pragma unroll
    for (int mt = 0; mt < 4; ++mt)
        #pragma unroll
        for (int nt = 0; nt < 4; ++nt)
            acc[mt][nt] = (f32x4){0.f, 0.f, 0.f, 0.f};

    // ---- Layer 1 ----
    for (int ks = 0; ks < K1 / 32; ++ks) {
        const int k0 = ks * 32;
        {
            int e  = tid >> 2, c = tid & 3;
            int kk = k0 + c * 8;
            if (kk < 128) {
                *(float4*)&sA[e * LDA + c * 8] =
                    *(const float4*)(nodef_bf + (size_t)s_src[e] * ND + kk);
            } else if (kk < 256) {
                *(float4*)&sA[e * LDA + c * 8] =
                    *(const float4*)(nodef_bf + (size_t)s_dst[e] * ND + (kk - 128));
            } else {
                const float* fp = edgef + (size_t)s_eid[e] * ED + (kk - 256);
                float4 v0 = *(const float4*)fp;
                float4 v1 = *(const float4*)(fp + 4);
                ushort4 o0, o1;
                o0.x = f2bf(v0.x); o0.y = f2bf(v0.y); o0.z = f2bf(v0.z); o0.w = f2bf(v0.w);
                o1.x = f2bf(v1.x); o1.y = f2bf(v1.y); o1.z = f2bf(v1.z); o1.w = f2bf(v1.w);
                *(ushort4*)&sA[e * LDA + c * 8]     = o0;
                *(ushort4*)&sA[e * LDA + c * 8 + 4] = o1;
            }
        }
        #pragma unroll
        for (int ci = 0; ci < 4; ++ci) {
            int c = tid + ci * 256;
            int n = c >> 2, sub = c & 3;
            *(float4*)&sB[n * LDB + sub * 8] =
                *(const float4*)&w1t[(size_t)n * K1 + k0 + sub * 8];
        }
        __syncthreads();

        bf16x8 af[4], bfg[4];
        #pragma unroll
        for (int mt = 0; mt < 4; ++mt)
            af[mt] = *(const bf16x8*)&sA[(mt * 16 + r16) * LDA + quad * 8];
        #pragma unroll
        for (int nt = 0; nt < 4; ++nt)
            bfg[nt] = *(const bf16x8*)&sB[(wave * 64 + nt * 16 + r16) * LDB + quad * 8];
        #pragma unroll
        for (int mt = 0; mt < 4; ++mt)
            #pragma unroll
            for (int nt = 0; nt < 4; ++nt)
                acc[mt][nt] = __builtin_amdgcn_mfma_f32_16x16x32_bf16(
                    af[mt], bfg[nt], acc[mt][nt], 0, 0, 0);
        __syncthreads();
    }

    // layer-1 epilogue -> sH
    #pragma unroll
    for (int nt = 0; nt < 4; ++nt) {
        int n = wave * 64 + nt * 16 + r16;
        float bias = b1m[n];
        #pragma unroll
        for (int mt = 0; mt < 4; ++mt) {
            #pragma unroll
            for (int r = 0; r < 4; ++r) {
                int m = mt * 16 + quad * 4 + r;
                sH[m * LDH + n] = f2bf(gelu_tanh(acc[mt][nt][r] + bias));
            }
        }
        #pragma unroll
        for (int mt = 0; mt < 4; ++mt)
            acc[mt][nt] = (f32x4){0.f, 0.f, 0.f, 0.f};
    }

    // ---- Layer 2 ----
    for (int ks = 0; ks < K2 / 32; ++ks) {
        const int k0 = ks * 32;
        #pragma unroll
        for (int ci = 0; ci < 4; ++ci) {
            int c = tid + ci * 256;
            int n = c >> 2, sub = c & 3;
            *(float4*)&sB[n * LDB + sub * 8] =
                *(const float4*)&w2t[(size_t)n * K2 + k0 + sub * 8];
        }
        __syncthreads();

        bf16x8 af[4], bfg[4];
        #pragma unroll
        for (int mt = 0; mt < 4; ++mt)
            af[mt] = *(const bf16x8*)&sH[(mt * 16 + r16) * LDH + k0 + quad * 8];
        #pragma unroll
        for (int nt = 0; nt < 4; ++nt)
            bfg[nt] = *(const bf16x8*)&sB[(wave * 64 + nt * 16 + r16) * LDB + quad * 8];
        #pragma unroll
        for (int mt = 0; mt < 4; ++mt)
            #pragma unroll
            for (int nt = 0; nt < 4; ++nt)
                acc[mt][nt] = __builtin_amdgcn_mfma_f32_16x16x32_bf16(
                    af[mt], bfg[nt], acc[mt][nt], 0, 0, 0);
        __syncthreads();
    }

    // ---- epilogue: C(+bias) -> fbuf, batched run-reduce by sorted dst ----
    #pragma unroll
    for (int nt = 0; nt < 4; ++nt) {
        int n = wave * 64 + nt * 16 + r16;
        float bias = b2m[n];
        #pragma unroll
        for (int mt = 0; mt < 4; ++mt) {
            #pragma unroll
            for (int r = 0; r < 4; ++r) {
                int m = mt * 16 + quad * 4 + r;
                fbuf[m * LDF + n] = acc[mt][nt][r] + bias;
            }
        }
    }
    __syncthreads();

    {
        const int cc = tid;
        int   cur  = s_dst[0];
        float racc = 0.f;
        for (int mb = 0; mb < TM; mb += 8) {
            float v[8];
            #pragma unroll
            for (int j = 0; j < 8; ++j)
                v[j] = fbuf[(mb + j) * LDF + cc];   // independent, batched
            #pragma unroll
            for (int j = 0; j < 8; ++j) {
                int d = s_dst[mb + j];              // LDS broadcast (uniform)
                if (d != cur) {
                    atomicAdd(&agg[(size_t)cur * HID + cc], racc);
                    cur = d; racc = v[j];
                } else {
                    racc += v[j];
                }
            }
        }
        atomicAdd(&agg[(size_t)cur * HID + cc], racc);
    }
}

// ---------- node MLP (MFMA) ----------
// PRET=true : weights pre-transposed bf16 in ws (w1ut/w2ut valid).
// PRET=false: weights fp32 k-major from d_in, transposed inline (Round-5-proven).
// Reads ZERO bytes of d_out in both modes (no cross-block race with out writes).

template <bool PRET>
__global__ __launch_bounds__(256) void node_mlp_mfma(
    const float* __restrict__ nodef,              // [BN,128] fp32
    const float* __restrict__ agg,                // [BN,256] fp32
    const float* __restrict__ W1u,                // [384,256] fp32 (PRET=false)
    const unsigned short* __restrict__ w1ut,      // [256][384] bf16 (PRET=true)
    const float* __restrict__ b1u,
    const float* __restrict__ W2u,                // [256,128] fp32 (PRET=false)
    const unsigned short* __restrict__ w2ut,      // [128][256] bf16 (PRET=true)
    const float* __restrict__ b2u,
    float* __restrict__ out)                      // [BN,128] fp32
{
    __shared__ __align__(16) unsigned short sA[TM * LDA];
    __shared__ __align__(16) unsigned short sB[HID * LDB];
    __shared__ __align__(16) unsigned short sH[TM * LDH];

    const int tid  = threadIdx.x;
    const int wave = tid >> 6;
    const int lane = tid & 63;
    const int quad = lane >> 4;
    const int r16  = lane & 15;
    const int n0   = blockIdx.x * TM;

    f32x4 acc[4][4];
    #pragma unroll
    for (int mt = 0; mt < 4; ++mt)
        #pragma unroll
        for (int nt = 0; nt < 4; ++nt)
            acc[mt][nt] = (f32x4){0.f, 0.f, 0.f, 0.f};

    // ---- Layer 1: u = gelu([nodef|agg] @ W1u + b1u), K=384 ----
    for (int ks = 0; ks < K1U / 32; ++ks) {
        const int k0 = ks * 32;
        {
            int e  = tid >> 2, c = tid & 3;
            int row = n0 + e; if (row >= BN) row = BN - 1;
            int kk = k0 + c * 8;
            const float* fp = (kk < 128)
                ? nodef + (size_t)row * ND + kk
                : agg   + (size_t)row * HID + (kk - 128);
            float4 v0 = *(const float4*)fp;
            float4 v1 = *(const float4*)(fp + 4);
            ushort4 o0, o1;
            o0.x = f2bf(v0.x); o0.y = f2bf(v0.y); o0.z = f2bf(v0.z); o0.w = f2bf(v0.w);
            o1.x = f2bf(v1.x); o1.y = f2bf(v1.y); o1.z = f2bf(v1.z); o1.w = f2bf(v1.w);
            *(ushort4*)&sA[e * LDA + c * 8]     = o0;
            *(ushort4*)&sA[e * LDA + c * 8 + 4] = o1;
        }
        if (PRET) {
            #pragma unroll
            for (int ci = 0; ci < 4; ++ci) {
                int c = tid + ci * 256;
                int n = c >> 2, sub = c & 3;
                *(float4*)&sB[n * LDB + sub * 8] =
                    *(const float4*)&w1ut[(size_t)n * K1U + k0 + sub * 8];
            }
        } else {
            #pragma unroll
            for (int it = 0; it < 4; ++it) {
                int u  = it * 256 + tid;
                int kp = u & 15;          // k-pair
                int nq = u >> 4;          // n-quad
                int k  = k0 + 2 * kp;
                float4 v0 = *(const float4*)&W1u[(size_t)k * HID + 4 * nq];
                float4 v1 = *(const float4*)&W1u[(size_t)(k + 1) * HID + 4 * nq];
                const float* a0 = (const float*)&v0;
                const float* a1 = (const float*)&v1;
                #pragma unroll
                for (int j = 0; j < 4; ++j) {
                    unsigned int pk = (unsigned int)f2bf(a0[j]) |
                                      ((unsigned int)f2bf(a1[j]) << 16);
                    *(unsigned int*)&sB[(4 * nq + j) * LDB + 2 * kp] = pk;
                }
            }
        }
        __syncthreads();

        bf16x8 af[4], bfg[4];
        #pragma unroll
        for (int mt = 0; mt < 4; ++mt)
            af[mt] = *(const bf16x8*)&sA[(mt * 16 + r16) * LDA + quad * 8];
        #pragma unroll
        for (int nt = 0; nt < 4; ++nt)
            bfg[nt] = *(const bf16x8*)&sB[(wave * 64 + nt * 16 + r16) * LDB + quad * 8];
        #pragma unroll
        for (int mt = 0; mt < 4; ++mt)
            #pragma unroll
            for (int nt = 0; nt < 4; ++nt)
                acc[mt][nt] = __builtin_amdgcn_mfma_f32_16x16x32_bf16(
                    af[mt], bfg[nt], acc[mt][nt], 0, 0, 0);
        __syncthreads();
    }

    // layer-1 epilogue -> sH
    #pragma unroll
    for (int nt = 0; nt < 4; ++nt) {
        int n = wave * 64 + nt * 16 + r16;
        float bias = b1u[n];
        #pragma unroll
        for (int mt = 0; mt < 4; ++mt) {
            #pragma unroll
            for (int r = 0; r < 4; ++r) {
                int m = mt * 16 + quad * 4 + r;
                sH[m * LDH + n] = f2bf(gelu_tanh(acc[mt][nt][r] + bias));
            }
        }
    }

    // ---- Layer 2: out = u @ W2u + b2u, 128 cols ----
    f32x4 acc2[4][2];
    #pragma unroll
    for (int mt = 0; mt < 4; ++mt)
        #pragma unroll
        for (int nt = 0; nt < 2; ++nt)
            acc2[mt][nt] = (f32x4){0.f, 0.f, 0.f, 0.f};

    for (int ks = 0; ks < K2 / 32; ++ks) {
        const int k0 = ks * 32;
        if (PRET) {
            #pragma unroll
            for (int it = 0; it < 2; ++it) {
                int c = it * 256 + tid;
                int n = c >> 2, sub = c & 3;   // n in 0..127
                *(float4*)&sB[n * LDB + sub * 8] =
                    *(const float4*)&w2ut[(size_t)n * K2 + k0 + sub * 8];
            }
        } else {
            #pragma unroll
            for (int it = 0; it < 2; ++it) {
                int u  = it * 256 + tid;
                int kp = u & 15;
                int nq = u >> 4;          // 0..31
                int k  = k0 + 2 * kp;
                float4 v0 = *(const float4*)&W2u[(size_t)k * NOUT + 4 * nq];
                float4 v1 = *(const float4*)&W2u[(size_t)(k + 1) * NOUT + 4 * nq];
                const float* a0 = (const float*)&v0;
                const float* a1 = (const float*)&v1;
                #pragma unroll
                for (int j = 0; j < 4; ++j) {
                    unsigned int pk = (unsigned int)f2bf(a0[j]) |
                                      ((unsigned int)f2bf(a1[j]) << 16);
                    *(unsigned int*)&sB[(4 * nq + j) * LDB + 2 * kp] = pk;
                }
            }
        }
        __syncthreads();   // sH writes (first iter) + sB staging visible

        bf16x8 af[4], bfg[2];
        #pragma unroll
        for (int mt = 0; mt < 4; ++mt)
            af[mt] = *(const bf16x8*)&sH[(mt * 16 + r16) * LDH + k0 + quad * 8];
        #pragma unroll
        for (int nt = 0; nt < 2; ++nt)
            bfg[nt] = *(const bf16x8*)&sB[(wave * 32 + nt * 16 + r16) * LDB + quad * 8];
        #pragma unroll
        for (int mt = 0; mt < 4; ++mt)
            #pragma unroll
            for (int nt = 0; nt < 2; ++nt)
                acc2[mt][nt] = __builtin_amdgcn_mfma_f32_16x16x32_bf16(
                    af[mt], bfg[nt], acc2[mt][nt], 0, 0, 0);
        __syncthreads();
    }

    #pragma unroll
    for (int nt = 0; nt < 2; ++nt) {
        int n = wave * 32 + nt * 16 + r16;
        float bias = b2u[n];
        #pragma unroll
        for (int mt = 0; mt < 4; ++mt) {
            #pragma unroll
            for (int r = 0; r < 4; ++r) {
                int m = mt * 16 + quad * 4 + r;
                if (n0 + m < BN)
                    out[(size_t)(n0 + m) * NOUT + n] = acc2[mt][nt][r] + bias;
            }
        }
    }
}

// ---------- launch ----------
// ws: agg [0 .. 20,480,000) — proven safe. If ws_size has >=262,144 B headroom,
// node weights (bf16, pre-transposed) also live in ws (fast path). Branching on
// ws_size is deterministic across calls (graph-capture safe).
// d_out stash — read ONLY by prep/sort/edge kernels, all of which complete
// before node_mlp_mfma (which writes d_out) launches:
//   nodef_bf [0 .. 5,120,000)
//   w1t      [5,120,000 .. 5,283,840)
//   w2t      [5,283,840 .. 5,414,912)
//   hist     [5,414,912 .. 5,494,912)
//   offs     [5,494,912 .. 5,574,912)
//   perm     [5,574,912 .. 6,854,912)   total < 10,240,000 B

extern "C" void kernel_launch(void* const* d_in, const int* in_sizes, int n_in,
                              void* d_out, int out_size, void* d_ws, size_t ws_size,
                              hipStream_t stream) {
    const float* nodef = (const float*)d_in[0];
    const int*   eidx  = (const int*)  d_in[1];
    const float* edgef = (const float*)d_in[2];
    const float* W1m   = (const float*)d_in[3];
    const float* b1m   = (const float*)d_in[4];
    const float* W2m   = (const float*)d_in[5];
    const float* b2m   = (const float*)d_in[6];
    const float* W1u   = (const float*)d_in[7];
    const float* b1u   = (const float*)d_in[8];
    const float* W2u   = (const float*)d_in[9];
    const float* b2u   = (const float*)d_in[10];
    float* out = (float*)d_out;

    char* wsb = (char*)d_ws;
    float* agg = (float*)wsb;    // [BN, 256] fp32 = 20,480,000 B

    const size_t AGG_B = (size_t)BN * HID * sizeof(float);        // 20,480,000
    const size_t W1UT_B = (size_t)K1U * HID * sizeof(unsigned short); // 196,608
    const size_t W2UT_B = (size_t)K2 * NOUT * sizeof(unsigned short); //  65,536
    const bool ws_pret = ws_size >= AGG_B + W1UT_B + W2UT_B;

    char* ob = (char*)d_out;
    unsigned short* nodef_bf = (unsigned short*)ob;
    unsigned short* w1t  = (unsigned short*)(ob + 5120000);
    unsigned short* w2t  = (unsigned short*)(ob + 5283840);
    int* hist            = (int*)(ob + 5414912);
    int* offs            = (int*)(ob + 5494912);
    int* perm            = (int*)(ob + 5574912);

    hipMemsetAsync(agg, 0, AGG_B, stream);
    hipMemsetAsync(hist, 0, BN * sizeof(int), stream);

    {
        int n4 = BN * ND / 4;
        f32_to_bf16_vec<<<(n4 + 255) / 256, 256, 0, stream>>>(nodef, nodef_bf, n4);
    }
    w_transpose_bf16<<<(K1 * HID + 255) / 256, 256, 0, stream>>>(W1m, w1t, K1, HID);
    w_transpose_bf16<<<(K2 * HID + 255) / 256, 256, 0, stream>>>(W2m, w2t, K2, HID);

    dst_hist<<<(BE + 255) / 256, 256, 0, stream>>>(eidx, hist);
    scan_bins<<<1, 1024, 0, stream>>>(hist, offs);
    dst_scatter<<<(BE + 255) / 256, 256, 0, stream>>>(eidx, offs, perm);

    edge_mlp_mfma<<<BE / TM, 256, 0, stream>>>(
        nodef_bf, eidx, edgef, perm, w1t, b1m, w2t, b2m, agg);

    if (ws_pret) {
        unsigned short* w1ut = (unsigned short*)(wsb + AGG_B);
        unsigned short* w2ut = (unsigned short*)(wsb + AGG_B + W1UT_B);
        w_transpose_bf16<<<(K1U * HID + 255) / 256, 256, 0, stream>>>(W1u, w1ut, K1U, HID);
        w_transpose_bf16<<<(K2 * NOUT + 255) / 256, 256, 0, stream>>>(W2u, w2ut, K2, NOUT);
        node_mlp_mfma<true><<<(BN + TM - 1) / TM, 256, 0, stream>>>(
            nodef, agg, nullptr, w1ut, b1u, nullptr, w2ut, b2u, out);
    } else {
        node_mlp_mfma<false><<<(BN + TM - 1) / TM, 256, 0, stream>>>(
            nodef, agg, W1u, nullptr, b1u, W2u, nullptr, b2u, out);
    }
}

// Round 8
// 425.352 us; speedup vs baseline: 4.7044x; 1.1111x over previous
//
#include <hip/hip_runtime.h>
#include <hip/hip_bf16.h>
#include <math.h>

#define BATCH   2
#define N_NODES 10000
#define E_EDGES 160000
#define BN      (BATCH * N_NODES)       // 20000
#define BE      (BATCH * E_EDGES)       // 320000
#define ND      128
#define ED      64
#define HID     256
#define K1      320   // 2*ND + ED
#define K2      256
#define K1U     384   // ND + HID
#define NOUT    128
#define TM      64    // rows per block
#define LDA     40    // node-kernel A stride (bf16)
#define LDB     40    // node-kernel B stride (bf16)
#define LDH     264   // H LDS row stride (bf16), 256+8
#define SCAN_BLOCKS ((BN + 1023) / 1024)   // 20

typedef __attribute__((ext_vector_type(8))) short bf16x8;
typedef __attribute__((ext_vector_type(4))) float f32x4;

// fast tanh-gelu: tanh(u) = 1 - 2/(exp(2u)+1); both tails saturate correctly.
__device__ __forceinline__ float gelu_tanh(float x) {
    float u = 0.7978845608028654f * (x + 0.044715f * x * x * x);
    float e = __expf(2.0f * u);
    float t = 1.0f - 2.0f * __builtin_amdgcn_rcpf(e + 1.0f);
    return 0.5f * x * (1.0f + t);
}

__device__ __forceinline__ unsigned short f2bf(float f) {
    __hip_bfloat16 h = __float2bfloat16(f);
    return *reinterpret_cast<unsigned short*>(&h);
}

__device__ __forceinline__ float bf2f(unsigned short u) {
    unsigned int x = ((unsigned int)u) << 16;
    return *reinterpret_cast<float*>(&x);
}

// async global->LDS DMA, 16 B per lane; lds dest = wave-uniform base + lane*16
__device__ __forceinline__ void gl2lds16(const void* g, void* l) {
    __builtin_amdgcn_global_load_lds(
        (const __attribute__((address_space(1))) unsigned int*)g,
        (__attribute__((address_space(3))) unsigned int*)l,
        16, 0, 0);
}

// ---------- prep kernels ----------

__global__ __launch_bounds__(256) void f32_to_bf16_vec(
    const float* __restrict__ in, unsigned short* __restrict__ out, int n4)
{
    int i = blockIdx.x * blockDim.x + threadIdx.x;
    if (i < n4) {
        float4 v = ((const float4*)in)[i];
        ushort4 o;
        o.x = f2bf(v.x); o.y = f2bf(v.y); o.z = f2bf(v.z); o.w = f2bf(v.w);
        ((ushort4*)out)[i] = o;
    }
}

__global__ __launch_bounds__(256) void w_transpose_bf16(
    const float* __restrict__ w, unsigned short* __restrict__ wt, int K, int N)
{
    int id = blockIdx.x * blockDim.x + threadIdx.x;
    if (id < K * N) {
        int k = id % K;
        int n = id / K;
        wt[id] = f2bf(w[k * N + n]);
    }
}

__global__ __launch_bounds__(256) void dst_hist(
    const int* __restrict__ eidx, int* __restrict__ hist)
{
    int e = blockIdx.x * blockDim.x + threadIdx.x;
    if (e < BE) {
        int dst = eidx[2 * e + 1];
        int b   = e / E_EDGES;
        atomicAdd(&hist[b * N_NODES + dst], 1);
    }
}

// ---------- hierarchical scan (3 small kernels) ----------

__global__ __launch_bounds__(1024) void scan_partial(
    const int* __restrict__ hist, int* __restrict__ offs, int* __restrict__ bsum)
{
    __shared__ int buf[1024];
    int tid = threadIdx.x;
    int i   = blockIdx.x * 1024 + tid;
    int v   = (i < BN) ? hist[i] : 0;
    buf[tid] = v;
    __syncthreads();
    #pragma unroll
    for (int d = 1; d < 1024; d <<= 1) {
        int t = (tid >= d) ? buf[tid - d] : 0;
        __syncthreads();
        buf[tid] += t;
        __syncthreads();
    }
    int incl = buf[tid];
    if (i < BN) offs[i] = incl - v;
    if (tid == 1023) bsum[blockIdx.x] = incl;
}

__global__ __launch_bounds__(64) void scan_sums(int* __restrict__ bsum)
{
    if (threadIdx.x == 0) {
        int acc = 0;
        for (int b = 0; b < SCAN_BLOCKS; ++b) {
            int t = bsum[b];
            bsum[b] = acc;
            acc += t;
        }
    }
}

__global__ __launch_bounds__(1024) void scan_add(
    int* __restrict__ offs, const int* __restrict__ bsum)
{
    int i = blockIdx.x * 1024 + threadIdx.x;
    if (i < BN) offs[i] += bsum[blockIdx.x];
}

__global__ __launch_bounds__(256) void dst_scatter(
    const int* __restrict__ eidx, int* __restrict__ offs, int* __restrict__ perm)
{
    int e = blockIdx.x * blockDim.x + threadIdx.x;
    if (e < BE) {
        int dst  = eidx[2 * e + 1];
        int b    = e / E_EDGES;
        int pos  = atomicAdd(&offs[b * N_NODES + dst], 1);
        perm[pos] = e;
    }
}

// ---------- edge MLP (MFMA, DMA-staged) + sorted scatter ----------
// smem layout (all unpadded for DMA except sH):
//   sA [0 .. 4096)            64 rows x 32 k bf16, stride 32
//   sB [4096 .. 20480)        256 n x 32 k bf16, stride 32
//   sH [20480 .. 54272)       64 rows x 264 bf16 (padded; written from regs)
//   fbuf (bf16) aliases sH (stride 264) for the epilogue run-reduce
#define SMEM_A  0
#define SMEM_B  4096
#define SMEM_H  20480
#define EDGE_SMEM 54272

__global__ __launch_bounds__(256) void edge_mlp_mfma(
    const unsigned short* __restrict__ nodef_bf,
    const int*            __restrict__ eidx,
    const float*          __restrict__ edgef,
    const int*            __restrict__ perm,
    const unsigned short* __restrict__ w1t,       // [256][320] bf16 n-major
    const float*          __restrict__ b1m,
    const unsigned short* __restrict__ w2t,       // [256][256] bf16 n-major
    const float*          __restrict__ b2m,
    float* __restrict__ agg)
{
    __shared__ __align__(16) char smem[EDGE_SMEM];
    unsigned short* sA = (unsigned short*)(smem + SMEM_A);
    unsigned short* sB = (unsigned short*)(smem + SMEM_B);
    unsigned short* sH = (unsigned short*)(smem + SMEM_H);
    unsigned short* fb = sH;   // epilogue alias, stride LDH
    __shared__ int s_src[TM];
    __shared__ int s_dst[TM];
    __shared__ int s_eid[TM];

    const int tid  = threadIdx.x;
    const int wave = tid >> 6;
    const int lane = tid & 63;
    const int quad = lane >> 4;
    const int r16  = lane & 15;
    const int be0  = blockIdx.x * TM;

    if (tid < TM) {
        int eid = perm[be0 + tid];
        int b   = eid / E_EDGES;
        int2 se = ((const int2*)eidx)[eid];
        s_eid[tid] = eid;
        s_src[tid] = b * N_NODES + se.x;
        s_dst[tid] = b * N_NODES + se.y;
    }
    __syncthreads();

    f32x4 acc[4][4];
    #pragma unroll
    for (int mt = 0; mt < 4; ++mt)
        #pragma unroll
        for (int nt = 0; nt < 4; ++nt)
            acc[mt][nt] = (f32x4){0.f, 0.f, 0.f, 0.f};

    // ---- Layer 1: K=320, 10 k-steps ----
    for (int ks = 0; ks < K1 / 32; ++ks) {
        const int k0 = ks * 32;
        // A stage: one DMA inst per wave (ks<8: node features, bf16 in global)
        if (ks < 8) {
            int i  = wave * 64 + lane;
            int e  = i >> 2, c = i & 3;
            int kk = k0 + c * 8;
            const unsigned short* gs = (ks < 4)
                ? nodef_bf + (size_t)s_src[e] * ND + kk
                : nodef_bf + (size_t)s_dst[e] * ND + (kk - 128);
            gl2lds16(gs, smem + SMEM_A + wave * 1024);
        } else {
            // edge features: fp32 global -> bf16 LDS, manual
            int e  = tid >> 2, c = tid & 3;
            int kk = k0 + c * 8 - 256;
            const float* fp = edgef + (size_t)s_eid[e] * ED + kk;
            float4 v0 = *(const float4*)fp;
            float4 v1 = *(const float4*)(fp + 4);
            ushort4 o0, o1;
            o0.x = f2bf(v0.x); o0.y = f2bf(v0.y); o0.z = f2bf(v0.z); o0.w = f2bf(v0.w);
            o1.x = f2bf(v1.x); o1.y = f2bf(v1.y); o1.z = f2bf(v1.z); o1.w = f2bf(v1.w);
            *(ushort4*)&sA[e * 32 + c * 8]     = o0;
            *(ushort4*)&sA[e * 32 + c * 8 + 4] = o1;
        }
        // B stage: 4 DMA insts per wave (256 rows x 32 k = 16 KB)
        #pragma unroll
        for (int j = 0; j < 4; ++j) {
            int i   = (wave * 4 + j) * 64 + lane;
            int n   = i >> 2, sub = i & 3;
            gl2lds16(w1t + (size_t)n * K1 + k0 + sub * 8,
                     smem + SMEM_B + (wave * 4 + j) * 1024);
        }
        __syncthreads();

        bf16x8 af[4], bfg[4];
        #pragma unroll
        for (int mt = 0; mt < 4; ++mt)
            af[mt] = *(const bf16x8*)&sA[(mt * 16 + r16) * 32 + quad * 8];
        #pragma unroll
        for (int nt = 0; nt < 4; ++nt)
            bfg[nt] = *(const bf16x8*)&sB[(wave * 64 + nt * 16 + r16) * 32 + quad * 8];
        #pragma unroll
        for (int mt = 0; mt < 4; ++mt)
            #pragma unroll
            for (int nt = 0; nt < 4; ++nt)
                acc[mt][nt] = __builtin_amdgcn_mfma_f32_16x16x32_bf16(
                    af[mt], bfg[nt], acc[mt][nt], 0, 0, 0);
        __syncthreads();
    }

    // layer-1 epilogue -> sH
    #pragma unroll
    for (int nt = 0; nt < 4; ++nt) {
        int n = wave * 64 + nt * 16 + r16;
        float bias = b1m[n];
        #pragma unroll
        for (int mt = 0; mt < 4; ++mt) {
            #pragma unroll
            for (int r = 0; r < 4; ++r) {
                int m = mt * 16 + quad * 4 + r;
                sH[m * LDH + n] = f2bf(gelu_tanh(acc[mt][nt][r] + bias));
            }
        }
        #pragma unroll
        for (int mt = 0; mt < 4; ++mt)
            acc[mt][nt] = (f32x4){0.f, 0.f, 0.f, 0.f};
    }

    // ---- Layer 2: K=256, 8 k-steps ----
    for (int ks = 0; ks < K2 / 32; ++ks) {
        const int k0 = ks * 32;
        #pragma unroll
        for (int j = 0; j < 4; ++j) {
            int i   = (wave * 4 + j) * 64 + lane;
            int n   = i >> 2, sub = i & 3;
            gl2lds16(w2t + (size_t)n * K2 + k0 + sub * 8,
                     smem + SMEM_B + (wave * 4 + j) * 1024);
        }
        __syncthreads();   // also fences sH writes on first iter

        bf16x8 af[4], bfg[4];
        #pragma unroll
        for (int mt = 0; mt < 4; ++mt)
            af[mt] = *(const bf16x8*)&sH[(mt * 16 + r16) * LDH + k0 + quad * 8];
        #pragma unroll
        for (int nt = 0; nt < 4; ++nt)
            bfg[nt] = *(const bf16x8*)&sB[(wave * 64 + nt * 16 + r16) * 32 + quad * 8];
        #pragma unroll
        for (int mt = 0; mt < 4; ++mt)
            #pragma unroll
            for (int nt = 0; nt < 4; ++nt)
                acc[mt][nt] = __builtin_amdgcn_mfma_f32_16x16x32_bf16(
                    af[mt], bfg[nt], acc[mt][nt], 0, 0, 0);
        __syncthreads();
    }

    // ---- epilogue: C(+bias) -> fb (bf16, aliases sH), run-reduce by dst ----
    #pragma unroll
    for (int nt = 0; nt < 4; ++nt) {
        int n = wave * 64 + nt * 16 + r16;
        float bias = b2m[n];
        #pragma unroll
        for (int mt = 0; mt < 4; ++mt) {
            #pragma unroll
            for (int r = 0; r < 4; ++r) {
                int m = mt * 16 + quad * 4 + r;
                fb[m * LDH + n] = f2bf(acc[mt][nt][r] + bias);
            }
        }
    }
    __syncthreads();

    {
        const int cc = tid;
        int   cur  = s_dst[0];
        float racc = 0.f;
        for (int mb = 0; mb < TM; mb += 8) {
            float v[8];
            #pragma unroll
            for (int j = 0; j < 8; ++j)
                v[j] = bf2f(fb[(mb + j) * LDH + cc]);   // independent, batched
            #pragma unroll
            for (int j = 0; j < 8; ++j) {
                int d = s_dst[mb + j];                  // LDS broadcast (uniform)
                if (d != cur) {
                    atomicAdd(&agg[(size_t)cur * HID + cc], racc);
                    cur = d; racc = v[j];
                } else {
                    racc += v[j];
                }
            }
        }
        atomicAdd(&agg[(size_t)cur * HID + cc], racc);
    }
}

// ---------- node MLP (MFMA) ----------
// PRET=true : weights pre-transposed bf16 in ws. PRET=false: inline transpose.
// Reads ZERO bytes of d_out in both modes.

template <bool PRET>
__global__ __launch_bounds__(256) void node_mlp_mfma(
    const float* __restrict__ nodef,
    const float* __restrict__ agg,
    const float* __restrict__ W1u,
    const unsigned short* __restrict__ w1ut,
    const float* __restrict__ b1u,
    const float* __restrict__ W2u,
    const unsigned short* __restrict__ w2ut,
    const float* __restrict__ b2u,
    float* __restrict__ out)
{
    __shared__ __align__(16) unsigned short sA[TM * LDA];
    __shared__ __align__(16) unsigned short sB[HID * LDB];
    __shared__ __align__(16) unsigned short sH[TM * LDH];

    const int tid  = threadIdx.x;
    const int wave = tid >> 6;
    const int lane = tid & 63;
    const int quad = lane >> 4;
    const int r16  = lane & 15;
    const int n0   = blockIdx.x * TM;

    f32x4 acc[4][4];
    #pragma unroll
    for (int mt = 0; mt < 4; ++mt)
        #pragma unroll
        for (int nt = 0; nt < 4; ++nt)
            acc[mt][nt] = (f32x4){0.f, 0.f, 0.f, 0.f};

    for (int ks = 0; ks < K1U / 32; ++ks) {
        const int k0 = ks * 32;
        {
            int e  = tid >> 2, c = tid & 3;
            int row = n0 + e; if (row >= BN) row = BN - 1;
            int kk = k0 + c * 8;
            const float* fp = (kk < 128)
                ? nodef + (size_t)row * ND + kk
                : agg   + (size_t)row * HID + (kk - 128);
            float4 v0 = *(const float4*)fp;
            float4 v1 = *(const float4*)(fp + 4);
            ushort4 o0, o1;
            o0.x = f2bf(v0.x); o0.y = f2bf(v0.y); o0.z = f2bf(v0.z); o0.w = f2bf(v0.w);
            o1.x = f2bf(v1.x); o1.y = f2bf(v1.y); o1.z = f2bf(v1.z); o1.w = f2bf(v1.w);
            *(ushort4*)&sA[e * LDA + c * 8]     = o0;
            *(ushort4*)&sA[e * LDA + c * 8 + 4] = o1;
        }
        if (PRET) {
            #pragma unroll
            for (int ci = 0; ci < 4; ++ci) {
                int c = tid + ci * 256;
                int n = c >> 2, sub = c & 3;
                *(float4*)&sB[n * LDB + sub * 8] =
                    *(const float4*)&w1ut[(size_t)n * K1U + k0 + sub * 8];
            }
        } else {
            #pragma unroll
            for (int it = 0; it < 4; ++it) {
                int u  = it * 256 + tid;
                int kp = u & 15;
                int nq = u >> 4;
                int k  = k0 + 2 * kp;
                float4 v0 = *(const float4*)&W1u[(size_t)k * HID + 4 * nq];
                float4 v1 = *(const float4*)&W1u[(size_t)(k + 1) * HID + 4 * nq];
                const float* a0 = (const float*)&v0;
                const float* a1 = (const float*)&v1;
                #pragma unroll
                for (int j = 0; j < 4; ++j) {
                    unsigned int pk = (unsigned int)f2bf(a0[j]) |
                                      ((unsigned int)f2bf(a1[j]) << 16);
                    *(unsigned int*)&sB[(4 * nq + j) * LDB + 2 * kp] = pk;
                }
            }
        }
        __syncthreads();

        bf16x8 af[4], bfg[4];
        #pragma unroll
        for (int mt = 0; mt < 4; ++mt)
            af[mt] = *(const bf16x8*)&sA[(mt * 16 + r16) * LDA + quad * 8];
        #pragma unroll
        for (int nt = 0; nt < 4; ++nt)
            bfg[nt] = *(const bf16x8*)&sB[(wave * 64 + nt * 16 + r16) * LDB + quad * 8];
        #pragma unroll
        for (int mt = 0; mt < 4; ++mt)
            #pragma unroll
            for (int nt = 0; nt < 4; ++nt)
                acc[mt][nt] = __builtin_amdgcn_mfma_f32_16x16x32_bf16(
                    af[mt], bfg[nt], acc[mt][nt], 0, 0, 0);
        __syncthreads();
    }

    #pragma unroll
    for (int nt = 0; nt < 4; ++nt) {
        int n = wave * 64 + nt * 16 + r16;
        float bias = b1u[n];
        #pragma unroll
        for (int mt = 0; mt < 4; ++mt) {
            #pragma unroll
            for (int r = 0; r < 4; ++r) {
                int m = mt * 16 + quad * 4 + r;
                sH[m * LDH + n] = f2bf(gelu_tanh(acc[mt][nt][r] + bias));
            }
        }
    }

    f32x4 acc2[4][2];
    #pragma unroll
    for (int mt = 0; mt < 4; ++mt)
        #pragma unroll
        for (int nt = 0; nt < 2; ++nt)
            acc2[mt][nt] = (f32x4){0.f, 0.f, 0.f, 0.f};

    for (int ks = 0; ks < K2 / 32; ++ks) {
        const int k0 = ks * 32;
        if (PRET) {
            #pragma unroll
            for (int it = 0; it < 2; ++it) {
                int c = it * 256 + tid;
                int n = c >> 2, sub = c & 3;
                *(float4*)&sB[n * LDB + sub * 8] =
                    *(const float4*)&w2ut[(size_t)n * K2 + k0 + sub * 8];
            }
        } else {
            #pragma unroll
            for (int it = 0; it < 2; ++it) {
                int u  = it * 256 + tid;
                int kp = u & 15;
                int nq = u >> 4;
                int k  = k0 + 2 * kp;
                float4 v0 = *(const float4*)&W2u[(size_t)k * NOUT + 4 * nq];
                float4 v1 = *(const float4*)&W2u[(size_t)(k + 1) * NOUT + 4 * nq];
                const float* a0 = (const float*)&v0;
                const float* a1 = (const float*)&v1;
                #pragma unroll
                for (int j = 0; j < 4; ++j) {
                    unsigned int pk = (unsigned int)f2bf(a0[j]) |
                                      ((unsigned int)f2bf(a1[j]) << 16);
                    *(unsigned int*)&sB[(4 * nq + j) * LDB + 2 * kp] = pk;
                }
            }
        }
        __syncthreads();

        bf16x8 af[4], bfg[2];
        #pragma unroll
        for (int mt = 0; mt < 4; ++mt)
            af[mt] = *(const bf16x8*)&sH[(mt * 16 + r16) * LDH + k0 + quad * 8];
        #pragma unroll
        for (int nt = 0; nt < 2; ++nt)
            bfg[nt] = *(const bf16x8*)&sB[(wave * 32 + nt * 16 + r16) * LDB + quad * 8];
        #pragma unroll
        for (int mt = 0; mt < 4; ++mt)
            #pragma unroll
            for (int nt = 0; nt < 2; ++nt)
                acc2[mt][nt] = __builtin_amdgcn_mfma_f32_16x16x32_bf16(
                    af[mt], bfg[nt], acc2[mt][nt], 0, 0, 0);
        __syncthreads();
    }

    #pragma unroll
    for (int nt = 0; nt < 2; ++nt) {
        int n = wave * 32 + nt * 16 + r16;
        float bias = b2u[n];
        #pragma unroll
        for (int mt = 0; mt < 4; ++mt) {
            #pragma unroll
            for (int r = 0; r < 4; ++r) {
                int m = mt * 16 + quad * 4 + r;
                if (n0 + m < BN)
                    out[(size_t)(n0 + m) * NOUT + n] = acc2[mt][nt][r] + bias;
            }
        }
    }
}

// ---------- launch ----------
// ws: agg [0 .. 20,480,000) proven; node weights in ws iff headroom.
// d_out stash (read only before node_mlp_mfma runs):
//   nodef_bf [0 .. 5,120,000)
//   w1t      [5,120,000 .. 5,283,840)
//   w2t      [5,283,840 .. 5,414,912)
//   hist     [5,414,912 .. 5,494,912)
//   offs     [5,494,912 .. 5,574,912)
//   perm     [5,574,912 .. 6,854,912)
//   bsum     [6,854,912 .. 6,855,040)   total < 10,240,000 B

extern "C" void kernel_launch(void* const* d_in, const int* in_sizes, int n_in,
                              void* d_out, int out_size, void* d_ws, size_t ws_size,
                              hipStream_t stream) {
    const float* nodef = (const float*)d_in[0];
    const int*   eidx  = (const int*)  d_in[1];
    const float* edgef = (const float*)d_in[2];
    const float* W1m   = (const float*)d_in[3];
    const float* b1m   = (const float*)d_in[4];
    const float* W2m   = (const float*)d_in[5];
    const float* b2m   = (const float*)d_in[6];
    const float* W1u   = (const float*)d_in[7];
    const float* b1u   = (const float*)d_in[8];
    const float* W2u   = (const float*)d_in[9];
    const float* b2u   = (const float*)d_in[10];
    float* out = (float*)d_out;

    char* wsb = (char*)d_ws;
    float* agg = (float*)wsb;

    const size_t AGG_B  = (size_t)BN * HID * sizeof(float);
    const size_t W1UT_B = (size_t)K1U * HID * sizeof(unsigned short);
    const size_t W2UT_B = (size_t)K2 * NOUT * sizeof(unsigned short);
    const bool ws_pret = ws_size >= AGG_B + W1UT_B + W2UT_B;

    char* ob = (char*)d_out;
    unsigned short* nodef_bf = (unsigned short*)ob;
    unsigned short* w1t  = (unsigned short*)(ob + 5120000);
    unsigned short* w2t  = (unsigned short*)(ob + 5283840);
    int* hist            = (int*)(ob + 5414912);
    int* offs            = (int*)(ob + 5494912);
    int* perm            = (int*)(ob + 5574912);
    int* bsum            = (int*)(ob + 6854912);

    hipMemsetAsync(agg, 0, AGG_B, stream);
    hipMemsetAsync(hist, 0, BN * sizeof(int), stream);

    {
        int n4 = BN * ND / 4;
        f32_to_bf16_vec<<<(n4 + 255) / 256, 256, 0, stream>>>(nodef, nodef_bf, n4);
    }
    w_transpose_bf16<<<(K1 * HID + 255) / 256, 256, 0, stream>>>(W1m, w1t, K1, HID);
    w_transpose_bf16<<<(K2 * HID + 255) / 256, 256, 0, stream>>>(W2m, w2t, K2, HID);

    dst_hist<<<(BE + 255) / 256, 256, 0, stream>>>(eidx, hist);
    scan_partial<<<SCAN_BLOCKS, 1024, 0, stream>>>(hist, offs, bsum);
    scan_sums<<<1, 64, 0, stream>>>(bsum);
    scan_add<<<SCAN_BLOCKS, 1024, 0, stream>>>(offs, bsum);
    dst_scatter<<<(BE + 255) / 256, 256, 0, stream>>>(eidx, offs, perm);

    edge_mlp_mfma<<<BE / TM, 256, 0, stream>>>(
        nodef_bf, eidx, edgef, perm, w1t, b1m, w2t, b2m, agg);

    if (ws_pret) {
        unsigned short* w1ut = (unsigned short*)(wsb + AGG_B);
        unsigned short* w2ut = (unsigned short*)(wsb + AGG_B + W1UT_B);
        w_transpose_bf16<<<(K1U * HID + 255) / 256, 256, 0, stream>>>(W1u, w1ut, K1U, HID);
        w_transpose_bf16<<<(K2 * NOUT + 255) / 256, 256, 0, stream>>>(W2u, w2ut, K2, NOUT);
        node_mlp_mfma<true><<<(BN + TM - 1) / TM, 256, 0, stream>>>(
            nodef, agg, nullptr, w1ut, b1u, nullptr, w2ut, b2u, out);
    } else {
        node_mlp_mfma<false><<<(BN + TM - 1) / TM, 256, 0, stream>>>(
            nodef, agg, W1u, nullptr, b1u, W2u, nullptr, b2u, out);
    }
}

// Round 9
// 418.322 us; speedup vs baseline: 4.7834x; 1.0168x over previous
//
#include <hip/hip_runtime.h>
#include <hip/hip_bf16.h>
#include <math.h>

#define BATCH   2
#define N_NODES 10000
#define E_EDGES 160000
#define BN      (BATCH * N_NODES)       // 20000
#define BE      (BATCH * E_EDGES)       // 320000
#define ND      128
#define ED      64
#define HID     256
#define K1      320   // 2*ND + ED
#define K2      256
#define K1U     384   // ND + HID
#define NOUT    128
#define TM      64    // node-kernel rows per block
#define TME     128   // edge-kernel rows per block
#define LDA     40    // node-kernel A stride (bf16)
#define LDB     40    // node-kernel B stride (bf16)
#define LDH     264   // H stride (bf16), 256+8
#define SCAN_BLOCKS ((BN + 1023) / 1024)   // 20

typedef __attribute__((ext_vector_type(8))) short bf16x8;
typedef __attribute__((ext_vector_type(4))) float f32x4;

// fast tanh-gelu: tanh(u) = 1 - 2/(exp(2u)+1); both tails saturate correctly.
__device__ __forceinline__ float gelu_tanh(float x) {
    float u = 0.7978845608028654f * (x + 0.044715f * x * x * x);
    float e = __expf(2.0f * u);
    float t = 1.0f - 2.0f * __builtin_amdgcn_rcpf(e + 1.0f);
    return 0.5f * x * (1.0f + t);
}

__device__ __forceinline__ unsigned short f2bf(float f) {
    __hip_bfloat16 h = __float2bfloat16(f);
    return *reinterpret_cast<unsigned short*>(&h);
}

__device__ __forceinline__ float bf2f(unsigned short u) {
    unsigned int x = ((unsigned int)u) << 16;
    return *reinterpret_cast<float*>(&x);
}

// async global->LDS DMA, 16 B per lane; lds dest = wave-uniform base + lane*16
__device__ __forceinline__ void gl2lds16(const void* g, void* l) {
    __builtin_amdgcn_global_load_lds(
        (const __attribute__((address_space(1))) unsigned int*)g,
        (__attribute__((address_space(3))) unsigned int*)l,
        16, 0, 0);
}

// ---------- prep kernels ----------

__global__ __launch_bounds__(256) void f32_to_bf16_vec(
    const float* __restrict__ in, unsigned short* __restrict__ out, int n4)
{
    int i = blockIdx.x * blockDim.x + threadIdx.x;
    if (i < n4) {
        float4 v = ((const float4*)in)[i];
        ushort4 o;
        o.x = f2bf(v.x); o.y = f2bf(v.y); o.z = f2bf(v.z); o.w = f2bf(v.w);
        ((ushort4*)out)[i] = o;
    }
}

__global__ __launch_bounds__(256) void w_transpose_bf16(
    const float* __restrict__ w, unsigned short* __restrict__ wt, int K, int N)
{
    int id = blockIdx.x * blockDim.x + threadIdx.x;
    if (id < K * N) {
        int k = id % K;
        int n = id / K;
        wt[id] = f2bf(w[k * N + n]);
    }
}

__global__ __launch_bounds__(256) void dst_hist(
    const int* __restrict__ eidx, int* __restrict__ hist)
{
    int e = blockIdx.x * blockDim.x + threadIdx.x;
    if (e < BE) {
        int dst = eidx[2 * e + 1];
        int b   = e / E_EDGES;
        atomicAdd(&hist[b * N_NODES + dst], 1);
    }
}

// ---------- hierarchical scan ----------

__global__ __launch_bounds__(1024) void scan_partial(
    const int* __restrict__ hist, int* __restrict__ offs, int* __restrict__ bsum)
{
    __shared__ int buf[1024];
    int tid = threadIdx.x;
    int i   = blockIdx.x * 1024 + tid;
    int v   = (i < BN) ? hist[i] : 0;
    buf[tid] = v;
    __syncthreads();
    #pragma unroll
    for (int d = 1; d < 1024; d <<= 1) {
        int t = (tid >= d) ? buf[tid - d] : 0;
        __syncthreads();
        buf[tid] += t;
        __syncthreads();
    }
    int incl = buf[tid];
    if (i < BN) offs[i] = incl - v;
    if (tid == 1023) bsum[blockIdx.x] = incl;
}

__global__ __launch_bounds__(64) void scan_sums(int* __restrict__ bsum)
{
    if (threadIdx.x == 0) {
        int acc = 0;
        for (int b = 0; b < SCAN_BLOCKS; ++b) {
            int t = bsum[b];
            bsum[b] = acc;
            acc += t;
        }
    }
}

__global__ __launch_bounds__(1024) void scan_add(
    int* __restrict__ offs, const int* __restrict__ bsum)
{
    int i = blockIdx.x * 1024 + threadIdx.x;
    if (i < BN) offs[i] += bsum[blockIdx.x];
}

__global__ __launch_bounds__(256) void dst_scatter(
    const int* __restrict__ eidx, int* __restrict__ offs, int* __restrict__ perm)
{
    int e = blockIdx.x * blockDim.x + threadIdx.x;
    if (e < BE) {
        int dst  = eidx[2 * e + 1];
        int b    = e / E_EDGES;
        int pos  = atomicAdd(&offs[b * N_NODES + dst], 1);
        perm[pos] = e;
    }
}

// ---------- edge MLP (MFMA, 128 rows, barrier-free per-wave K-loop) ----------
// LDS (149,504 B + idx; 1 block/CU on 160 KiB):
//   sA   [0 .. 65,536)        8 panels x [128 rows x 32 k] bf16 (node features)
//   sB   [65,536 .. 81,920)   8 waves x private 32-row x 32-k W slice
//   sH   [81,920 .. 149,504)  128 x 264 bf16; first 16 KB doubles as the two
//                             edge-feature A panels (consumed before H written)
#define SMEM_A  0
#define SMEM_B  65536
#define SMEM_H  81920
#define EDGE_SMEM 149504

__global__ __launch_bounds__(512) void edge_mlp_mfma(
    const unsigned short* __restrict__ nodef_bf,
    const int*            __restrict__ eidx,
    const float*          __restrict__ edgef,
    const int*            __restrict__ perm,
    const unsigned short* __restrict__ w1t,       // [256][320] bf16 n-major
    const float*          __restrict__ b1m,
    const unsigned short* __restrict__ w2t,       // [256][256] bf16 n-major
    const float*          __restrict__ b2m,
    float* __restrict__ agg)
{
    __shared__ __align__(16) char smem[EDGE_SMEM];
    unsigned short* sH = (unsigned short*)(smem + SMEM_H);
    unsigned short* sEdge = sH;   // edge-feature panels (pre-L1-epilogue only)
    __shared__ int s_src[TME];
    __shared__ int s_dst[TME];
    __shared__ int s_eid[TME];

    const int tid  = threadIdx.x;
    const int wave = tid >> 6;
    const int lane = tid & 63;
    const int quad = lane >> 4;
    const int r16  = lane & 15;
    const int be0  = blockIdx.x * TME;

    if (tid < TME) {
        int eid = perm[be0 + tid];
        int b   = eid / E_EDGES;
        int2 se = ((const int2*)eidx)[eid];
        s_eid[tid] = eid;
        s_src[tid] = b * N_NODES + se.x;
        s_dst[tid] = b * N_NODES + se.y;
    }
    __syncthreads();

    // ---- stage ALL of A once ----
    // node panels (k 0..255): 64 KB via DMA, 8 insts/wave
    #pragma unroll
    for (int j = 0; j < 8; ++j) {
        int i  = wave * 8 + j;          // 0..63
        int p  = i >> 3;                // panel 0..7
        int q  = i & 7;                 // 1 KB subchunk
        int er = q * 16 + (lane >> 2);  // edge row 0..127
        int c8 = (lane & 3) * 8;
        const unsigned short* gs = (p < 4)
            ? nodef_bf + (size_t)s_src[er] * ND + p * 32 + c8
            : nodef_bf + (size_t)s_dst[er] * ND + (p - 4) * 32 + c8;
        gl2lds16(gs, smem + SMEM_A + p * 8192 + q * 1024);
    }
    // edge panels (k 256..319): fp32 -> bf16 manual, into sEdge
    #pragma unroll
    for (int t = 0; t < 2; ++t) {
        int u   = tid * 2 + t;          // 0..1023
        int row = u >> 3;
        int c0  = (u & 7) * 8;          // 0..56
        const float* fp = edgef + (size_t)s_eid[row] * ED + c0;
        float4 v0 = *(const float4*)fp;
        float4 v1 = *(const float4*)(fp + 4);
        ushort4 o0, o1;
        o0.x = f2bf(v0.x); o0.y = f2bf(v0.y); o0.z = f2bf(v0.z); o0.w = f2bf(v0.w);
        o1.x = f2bf(v1.x); o1.y = f2bf(v1.y); o1.z = f2bf(v1.z); o1.w = f2bf(v1.w);
        int p2 = c0 >> 5, kk = c0 & 31;
        *(ushort4*)&sEdge[p2 * 4096 + row * 32 + kk]     = o0;
        *(ushort4*)&sEdge[p2 * 4096 + row * 32 + kk + 4] = o1;
    }
    __syncthreads();   // drains DMA (vmcnt0 at barrier) + LDS writes

    const unsigned short* sBw = (const unsigned short*)(smem + SMEM_B) + wave * 1024;

    f32x4 acc[8][2];
    #pragma unroll
    for (int mt = 0; mt < 8; ++mt)
        #pragma unroll
        for (int nt = 0; nt < 2; ++nt)
            acc[mt][nt] = (f32x4){0.f, 0.f, 0.f, 0.f};

    // ---- Layer 1: K=320, 10 k-steps, NO barriers (per-wave private B) ----
    for (int ks = 0; ks < K1 / 32; ++ks) {
        const unsigned short* pA = (ks < 8)
            ? (const unsigned short*)(smem + SMEM_A) + ks * 4096
            : sEdge + (ks - 8) * 4096;
        #pragma unroll
        for (int j = 0; j < 2; ++j) {
            int r = wave * 32 + j * 16 + (lane >> 2);
            gl2lds16(w1t + (size_t)r * K1 + ks * 32 + (lane & 3) * 8,
                     smem + SMEM_B + wave * 2048 + j * 1024);
        }
        __builtin_amdgcn_s_waitcnt(0x0F70);   // vmcnt(0), wave-local

        bf16x8 af[8], bfg[2];
        #pragma unroll
        for (int mt = 0; mt < 8; ++mt)
            af[mt] = *(const bf16x8*)&pA[(mt * 16 + r16) * 32 + quad * 8];
        #pragma unroll
        for (int nt = 0; nt < 2; ++nt)
            bfg[nt] = *(const bf16x8*)&sBw[(nt * 16 + r16) * 32 + quad * 8];
        #pragma unroll
        for (int mt = 0; mt < 8; ++mt)
            #pragma unroll
            for (int nt = 0; nt < 2; ++nt)
                acc[mt][nt] = __builtin_amdgcn_mfma_f32_16x16x32_bf16(
                    af[mt], bfg[nt], acc[mt][nt], 0, 0, 0);
        __builtin_amdgcn_sched_barrier(0);    // keep next DMA below these reads
    }
    __syncthreads();   // all waves done reading sEdge/sA

    // ---- layer-1 epilogue -> sH (overwrites sEdge region; fenced above) ----
    #pragma unroll
    for (int nt = 0; nt < 2; ++nt) {
        int n = wave * 32 + nt * 16 + r16;
        float bias = b1m[n];
        #pragma unroll
        for (int mt = 0; mt < 8; ++mt) {
            #pragma unroll
            for (int r = 0; r < 4; ++r) {
                int m = mt * 16 + quad * 4 + r;
                sH[m * LDH + n] = f2bf(gelu_tanh(acc[mt][nt][r] + bias));
            }
            acc[mt][nt] = (f32x4){0.f, 0.f, 0.f, 0.f};
        }
    }
    __syncthreads();   // sH visible to all waves

    // ---- Layer 2: K=256, 8 k-steps, NO barriers ----
    for (int ks = 0; ks < K2 / 32; ++ks) {
        #pragma unroll
        for (int j = 0; j < 2; ++j) {
            int r = wave * 32 + j * 16 + (lane >> 2);
            gl2lds16(w2t + (size_t)r * K2 + ks * 32 + (lane & 3) * 8,
                     smem + SMEM_B + wave * 2048 + j * 1024);
        }
        __builtin_amdgcn_s_waitcnt(0x0F70);

        bf16x8 af[8], bfg[2];
        #pragma unroll
        for (int mt = 0; mt < 8; ++mt)
            af[mt] = *(const bf16x8*)&sH[(mt * 16 + r16) * LDH + ks * 32 + quad * 8];
        #pragma unroll
        for (int nt = 0; nt < 2; ++nt)
            bfg[nt] = *(const bf16x8*)&sBw[(nt * 16 + r16) * 32 + quad * 8];
        #pragma unroll
        for (int mt = 0; mt < 8; ++mt)
            #pragma unroll
            for (int nt = 0; nt < 2; ++nt)
                acc[mt][nt] = __builtin_amdgcn_mfma_f32_16x16x32_bf16(
                    af[mt], bfg[nt], acc[mt][nt], 0, 0, 0);
        __builtin_amdgcn_sched_barrier(0);
    }
    __syncthreads();   // all waves done reading sH before fb overwrite

    // ---- epilogue: C2(+bias) -> fb (bf16, aliases sH), run-reduce ----
    unsigned short* fb = sH;
    #pragma unroll
    for (int nt = 0; nt < 2; ++nt) {
        int n = wave * 32 + nt * 16 + r16;
        float bias = b2m[n];
        #pragma unroll
        for (int mt = 0; mt < 8; ++mt) {
            #pragma unroll
            for (int r = 0; r < 4; ++r) {
                int m = mt * 16 + quad * 4 + r;
                fb[m * LDH + n] = f2bf(acc[mt][nt][r] + bias);
            }
        }
    }
    __syncthreads();

    {
        const int cc = tid & 255;          // column
        const int r0 = (tid >> 8) * 64;    // row-half base
        int   cur  = s_dst[r0];
        float racc = 0.f;
        for (int mb = 0; mb < 64; mb += 8) {
            float v[8];
            #pragma unroll
            for (int j = 0; j < 8; ++j)
                v[j] = bf2f(fb[(r0 + mb + j) * LDH + cc]);
            #pragma unroll
            for (int j = 0; j < 8; ++j) {
                int d = s_dst[r0 + mb + j];
                if (d != cur) {
                    atomicAdd(&agg[(size_t)cur * HID + cc], racc);
                    cur = d; racc = v[j];
                } else {
                    racc += v[j];
                }
            }
        }
        atomicAdd(&agg[(size_t)cur * HID + cc], racc);
    }
}

// ---------- node MLP (MFMA) ----------

template <bool PRET>
__global__ __launch_bounds__(256) void node_mlp_mfma(
    const float* __restrict__ nodef,
    const float* __restrict__ agg,
    const float* __restrict__ W1u,
    const unsigned short* __restrict__ w1ut,
    const float* __restrict__ b1u,
    const float* __restrict__ W2u,
    const unsigned short* __restrict__ w2ut,
    const float* __restrict__ b2u,
    float* __restrict__ out)
{
    __shared__ __align__(16) unsigned short sA[TM * LDA];
    __shared__ __align__(16) unsigned short sB[HID * LDB];
    __shared__ __align__(16) unsigned short sH[TM * LDH];

    const int tid  = threadIdx.x;
    const int wave = tid >> 6;
    const int lane = tid & 63;
    const int quad = lane >> 4;
    const int r16  = lane & 15;
    const int n0   = blockIdx.x * TM;

    f32x4 acc[4][4];
    #pragma unroll
    for (int mt = 0; mt < 4; ++mt)
        #pragma unroll
        for (int nt = 0; nt < 4; ++nt)
            acc[mt][nt] = (f32x4){0.f, 0.f, 0.f, 0.f};

    for (int ks = 0; ks < K1U / 32; ++ks) {
        const int k0 = ks * 32;
        {
            int e  = tid >> 2, c = tid & 3;
            int row = n0 + e; if (row >= BN) row = BN - 1;
            int kk = k0 + c * 8;
            const float* fp = (kk < 128)
                ? nodef + (size_t)row * ND + kk
                : agg   + (size_t)row * HID + (kk - 128);
            float4 v0 = *(const float4*)fp;
            float4 v1 = *(const float4*)(fp + 4);
            ushort4 o0, o1;
            o0.x = f2bf(v0.x); o0.y = f2bf(v0.y); o0.z = f2bf(v0.z); o0.w = f2bf(v0.w);
            o1.x = f2bf(v1.x); o1.y = f2bf(v1.y); o1.z = f2bf(v1.z); o1.w = f2bf(v1.w);
            *(ushort4*)&sA[e * LDA + c * 8]     = o0;
            *(ushort4*)&sA[e * LDA + c * 8 + 4] = o1;
        }
        if (PRET) {
            #pragma unroll
            for (int ci = 0; ci < 4; ++ci) {
                int c = tid + ci * 256;
                int n = c >> 2, sub = c & 3;
                *(float4*)&sB[n * LDB + sub * 8] =
                    *(const float4*)&w1ut[(size_t)n * K1U + k0 + sub * 8];
            }
        } else {
            #pragma unroll
            for (int it = 0; it < 4; ++it) {
                int u  = it * 256 + tid;
                int kp = u & 15;
                int nq = u >> 4;
                int k  = k0 + 2 * kp;
                float4 v0 = *(const float4*)&W1u[(size_t)k * HID + 4 * nq];
                float4 v1 = *(const float4*)&W1u[(size_t)(k + 1) * HID + 4 * nq];
                const float* a0 = (const float*)&v0;
                const float* a1 = (const float*)&v1;
                #pragma unroll
                for (int j = 0; j < 4; ++j) {
                    unsigned int pk = (unsigned int)f2bf(a0[j]) |
                                      ((unsigned int)f2bf(a1[j]) << 16);
                    *(unsigned int*)&sB[(4 * nq + j) * LDB + 2 * kp] = pk;
                }
            }
        }
        __syncthreads();

        bf16x8 af[4], bfg[4];
        #pragma unroll
        for (int mt = 0; mt < 4; ++mt)
            af[mt] = *(const bf16x8*)&sA[(mt * 16 + r16) * LDA + quad * 8];
        #pragma unroll
        for (int nt = 0; nt < 4; ++nt)
            bfg[nt] = *(const bf16x8*)&sB[(wave * 64 + nt * 16 + r16) * LDB + quad * 8];
        #pragma unroll
        for (int mt = 0; mt < 4; ++mt)
            #pragma unroll
            for (int nt = 0; nt < 4; ++nt)
                acc[mt][nt] = __builtin_amdgcn_mfma_f32_16x16x32_bf16(
                    af[mt], bfg[nt], acc[mt][nt], 0, 0, 0);
        __syncthreads();
    }

    #pragma unroll
    for (int nt = 0; nt < 4; ++nt) {
        int n = wave * 64 + nt * 16 + r16;
        float bias = b1u[n];
        #pragma unroll
        for (int mt = 0; mt < 4; ++mt) {
            #pragma unroll
            for (int r = 0; r < 4; ++r) {
                int m = mt * 16 + quad * 4 + r;
                sH[m * LDH + n] = f2bf(gelu_tanh(acc[mt][nt][r] + bias));
            }
        }
    }

    f32x4 acc2[4][2];
    #pragma unroll
    for (int mt = 0; mt < 4; ++mt)
        #pragma unroll
        for (int nt = 0; nt < 2; ++nt)
            acc2[mt][nt] = (f32x4){0.f, 0.f, 0.f, 0.f};

    for (int ks = 0; ks < K2 / 32; ++ks) {
        const int k0 = ks * 32;
        if (PRET) {
            #pragma unroll
            for (int it = 0; it < 2; ++it) {
                int c = it * 256 + tid;
                int n = c >> 2, sub = c & 3;
                *(float4*)&sB[n * LDB + sub * 8] =
                    *(const float4*)&w2ut[(size_t)n * K2 + k0 + sub * 8];
            }
        } else {
            #pragma unroll
            for (int it = 0; it < 2; ++it) {
                int u  = it * 256 + tid;
                int kp = u & 15;
                int nq = u >> 4;
                int k  = k0 + 2 * kp;
                float4 v0 = *(const float4*)&W2u[(size_t)k * NOUT + 4 * nq];
                float4 v1 = *(const float4*)&W2u[(size_t)(k + 1) * NOUT + 4 * nq];
                const float* a0 = (const float*)&v0;
                const float* a1 = (const float*)&v1;
                #pragma unroll
                for (int j = 0; j < 4; ++j) {
                    unsigned int pk = (unsigned int)f2bf(a0[j]) |
                                      ((unsigned int)f2bf(a1[j]) << 16);
                    *(unsigned int*)&sB[(4 * nq + j) * LDB + 2 * kp] = pk;
                }
            }
        }
        __syncthreads();

        bf16x8 af[4], bfg[2];
        #pragma unroll
        for (int mt = 0; mt < 4; ++mt)
            af[mt] = *(const bf16x8*)&sH[(mt * 16 + r16) * LDH + k0 + quad * 8];
        #pragma unroll
        for (int nt = 0; nt < 2; ++nt)
            bfg[nt] = *(const bf16x8*)&sB[(wave * 32 + nt * 16 + r16) * LDB + quad * 8];
        #pragma unroll
        for (int mt = 0; mt < 4; ++mt)
            #pragma unroll
            for (int nt = 0; nt < 2; ++nt)
                acc2[mt][nt] = __builtin_amdgcn_mfma_f32_16x16x32_bf16(
                    af[mt], bfg[nt], acc2[mt][nt], 0, 0, 0);
        __syncthreads();
    }

    #pragma unroll
    for (int nt = 0; nt < 2; ++nt) {
        int n = wave * 32 + nt * 16 + r16;
        float bias = b2u[n];
        #pragma unroll
        for (int mt = 0; mt < 4; ++mt) {
            #pragma unroll
            for (int r = 0; r < 4; ++r) {
                int m = mt * 16 + quad * 4 + r;
                if (n0 + m < BN)
                    out[(size_t)(n0 + m) * NOUT + n] = acc2[mt][nt][r] + bias;
            }
        }
    }
}

// ---------- launch ----------
// ws: agg [0 .. 20,480,000) proven; node weights in ws iff headroom.
// d_out stash (read only before node_mlp_mfma runs):
//   nodef_bf [0 .. 5,120,000)
//   w1t      [5,120,000 .. 5,283,840)
//   w2t      [5,283,840 .. 5,414,912)
//   hist     [5,414,912 .. 5,494,912)
//   offs     [5,494,912 .. 5,574,912)
//   perm     [5,574,912 .. 6,854,912)
//   bsum     [6,854,912 .. 6,855,040)   total < 10,240,000 B

extern "C" void kernel_launch(void* const* d_in, const int* in_sizes, int n_in,
                              void* d_out, int out_size, void* d_ws, size_t ws_size,
                              hipStream_t stream) {
    const float* nodef = (const float*)d_in[0];
    const int*   eidx  = (const int*)  d_in[1];
    const float* edgef = (const float*)d_in[2];
    const float* W1m   = (const float*)d_in[3];
    const float* b1m   = (const float*)d_in[4];
    const float* W2m   = (const float*)d_in[5];
    const float* b2m   = (const float*)d_in[6];
    const float* W1u   = (const float*)d_in[7];
    const float* b1u   = (const float*)d_in[8];
    const float* W2u   = (const float*)d_in[9];
    const float* b2u   = (const float*)d_in[10];
    float* out = (float*)d_out;

    char* wsb = (char*)d_ws;
    float* agg = (float*)wsb;

    const size_t AGG_B  = (size_t)BN * HID * sizeof(float);
    const size_t W1UT_B = (size_t)K1U * HID * sizeof(unsigned short);
    const size_t W2UT_B = (size_t)K2 * NOUT * sizeof(unsigned short);
    const bool ws_pret = ws_size >= AGG_B + W1UT_B + W2UT_B;

    char* ob = (char*)d_out;
    unsigned short* nodef_bf = (unsigned short*)ob;
    unsigned short* w1t  = (unsigned short*)(ob + 5120000);
    unsigned short* w2t  = (unsigned short*)(ob + 5283840);
    int* hist            = (int*)(ob + 5414912);
    int* offs            = (int*)(ob + 5494912);
    int* perm            = (int*)(ob + 5574912);
    int* bsum            = (int*)(ob + 6854912);

    hipMemsetAsync(agg, 0, AGG_B, stream);
    hipMemsetAsync(hist, 0, BN * sizeof(int), stream);

    {
        int n4 = BN * ND / 4;
        f32_to_bf16_vec<<<(n4 + 255) / 256, 256, 0, stream>>>(nodef, nodef_bf, n4);
    }
    w_transpose_bf16<<<(K1 * HID + 255) / 256, 256, 0, stream>>>(W1m, w1t, K1, HID);
    w_transpose_bf16<<<(K2 * HID + 255) / 256, 256, 0, stream>>>(W2m, w2t, K2, HID);

    dst_hist<<<(BE + 255) / 256, 256, 0, stream>>>(eidx, hist);
    scan_partial<<<SCAN_BLOCKS, 1024, 0, stream>>>(hist, offs, bsum);
    scan_sums<<<1, 64, 0, stream>>>(bsum);
    scan_add<<<SCAN_BLOCKS, 1024, 0, stream>>>(offs, bsum);
    dst_scatter<<<(BE + 255) / 256, 256, 0, stream>>>(eidx, offs, perm);

    edge_mlp_mfma<<<BE / TME, 512, 0, stream>>>(
        nodef_bf, eidx, edgef, perm, w1t, b1m, w2t, b2m, agg);

    if (ws_pret) {
        unsigned short* w1ut = (unsigned short*)(wsb + AGG_B);
        unsigned short* w2ut = (unsigned short*)(wsb + AGG_B + W1UT_B);
        w_transpose_bf16<<<(K1U * HID + 255) / 256, 256, 0, stream>>>(W1u, w1ut, K1U, HID);
        w_transpose_bf16<<<(K2 * NOUT + 255) / 256, 256, 0, stream>>>(W2u, w2ut, K2, NOUT);
        node_mlp_mfma<true><<<(BN + TM - 1) / TM, 256, 0, stream>>>(
            nodef, agg, nullptr, w1ut, b1u, nullptr, w2ut, b2u, out);
    } else {
        node_mlp_mfma<false><<<(BN + TM - 1) / TM, 256, 0, stream>>>(
            nodef, agg, W1u, nullptr, b1u, W2u, nullptr, b2u, out);
    }
}